// Round 12
// baseline (227.261 us; speedup 1.0000x reference)
//
#include <hip/hip_runtime.h>
#include <math.h>

#define SEQ 4096
#define DMODEL 1024
#define NH 16
#define DK 64
#define LDP 72   // padded LDS row (16-bit elems): conflict-free b64/b128 frag reads

typedef __bf16    bf16x8 __attribute__((ext_vector_type(8)));
typedef float     f32x4  __attribute__((ext_vector_type(4)));
typedef __fp16    fp16x2 __attribute__((ext_vector_type(2)));
typedef _Float16  h16x2  __attribute__((ext_vector_type(2)));
typedef _Float16  h16x4  __attribute__((ext_vector_type(4)));
typedef _Float16  h16x8  __attribute__((ext_vector_type(8)));

// global->LDS DMA, 16 B per lane; LDS dest = uniform base + lane*16 (no pad!)
#define GLOAD_LDS16(g, l) __builtin_amdgcn_global_load_lds(                     \
    (const __attribute__((address_space(1))) unsigned int*)(g),                 \
    (__attribute__((address_space(3))) unsigned int*)(l), 16, 0, 0)

// packed f32->f16 (RTZ), re-typed to _Float16x2
__device__ __forceinline__ h16x2 cvt_pk_h16(float a, float b) {
    fp16x2 r = __builtin_amdgcn_cvt_pkrtz(a, b);
    return __builtin_bit_cast(h16x2, r);
}

// raw v_exp_f32 (no denormal-guard expansion; inputs bounded)
#define EXP2R(x) __builtin_amdgcn_exp2f(x)

// ---------------------------------------------------------------------------
// Convert x (4M) + Wq/Wk/Wv/Wo (1M each) fp32 -> bf16 into contiguous ws.
// ---------------------------------------------------------------------------
__global__ __launch_bounds__(256)
void cvt_all(const float* __restrict__ x, const float* __restrict__ Wq,
             const float* __restrict__ Wk, const float* __restrict__ Wv,
             const float* __restrict__ Wo, __bf16* __restrict__ dst)
{
    const size_t M1 = 1u << 20;
    const size_t e = ((size_t)blockIdx.x * 256 + threadIdx.x) * 8;
    const float* src; size_t off;
    if      (e < 4*M1) { src = x;  off = e;        }
    else if (e < 5*M1) { src = Wq; off = e - 4*M1; }
    else if (e < 6*M1) { src = Wk; off = e - 5*M1; }
    else if (e < 7*M1) { src = Wv; off = e - 6*M1; }
    else               { src = Wo; off = e - 7*M1; }
    const float4 f0 = *reinterpret_cast<const float4*>(&src[off]);
    const float4 f1 = *reinterpret_cast<const float4*>(&src[off + 4]);
    bf16x8 pk;
    pk[0]=(__bf16)f0.x; pk[1]=(__bf16)f0.y; pk[2]=(__bf16)f0.z; pk[3]=(__bf16)f0.w;
    pk[4]=(__bf16)f1.x; pk[5]=(__bf16)f1.y; pk[6]=(__bf16)f1.z; pk[7]=(__bf16)f1.w;
    *reinterpret_cast<bf16x8*>(&dst[e]) = pk;
}

// ---------------------------------------------------------------------------
// 128(M) x 64(N) GEMM core with DMA staging (XOR chunk swizzle). Per wave:
// rows w*32..w*32+31, all 64 cols -> acc[2][4].
// ---------------------------------------------------------------------------
__device__ __forceinline__ void gemm_core64(const __bf16* __restrict__ A,
                                            const __bf16* __restrict__ W,
                                            int m0, int n0, int t,
                                            __bf16* AsF, __bf16* BsF,
                                            f32x4 acc[2][4])
{
    const int w = t >> 6, lane = t & 63, l15 = lane & 15, quad = lane >> 4;
    const int lr = lane >> 3, lc = lane & 7;
    for (int k0 = 0; k0 < DMODEL; k0 += 64) {
        __syncthreads();
        #pragma unroll
        for (int p = 0; p < 4; ++p) {
            const int n = w*4 + p;
            const int r = n*8 + lr;
            const int cl = lc ^ (r & 7);
            GLOAD_LDS16(&A[(size_t)(m0 + r) * DMODEL + k0 + cl*8], &AsF[n*512]);
        }
        #pragma unroll
        for (int p = 0; p < 2; ++p) {
            const int n = w*2 + p;
            const int r = n*8 + lr;
            const int cl = lc ^ (r & 7);
            GLOAD_LDS16(&W[(size_t)(n0 + r) * DMODEL + k0 + cl*8], &BsF[n*512]);
        }
        __syncthreads();
        #pragma unroll
        for (int kb = 0; kb < 2; ++kb) {
            const int phys = ((kb*4 + quad) ^ (l15 & 7)) * 8;
            bf16x8 af0 = *reinterpret_cast<const bf16x8*>(&AsF[(w*32 + l15)*64 + phys]);
            bf16x8 af1 = *reinterpret_cast<const bf16x8*>(&AsF[(w*32 + 16 + l15)*64 + phys]);
            #pragma unroll
            for (int ns = 0; ns < 4; ++ns) {
                const bf16x8 bfr = *reinterpret_cast<const bf16x8*>(&BsF[(ns*16 + l15)*64 + phys]);
                acc[0][ns] = __builtin_amdgcn_mfma_f32_16x16x32_bf16(af0, bfr, acc[0][ns], 0, 0, 0);
                acc[1][ns] = __builtin_amdgcn_mfma_f32_16x16x32_bf16(af1, bfr, acc[1][ns], 0, 0, 0);
            }
        }
    }
}

// ---------------------------------------------------------------------------
// Fused QKV projection -> fp16, V12: 128x64 tiles for 2x occupancy.
// Grid (48,32) = 1536 blocks = exactly 6/CU (LDS 24KB*6=144<=160KB), 24
// waves/CU vs the old 128x128 grid's 12 — the 2-barrier K-loop is latency
// bound and needs the TLP. launch_bounds(256,6) caps VGPR at 85 >= natural
// ~70 for this small core (no V8-style squeeze).
// [0,1024)=Q scaled 0.125*log2e; [1024,2048)=K; [2048,3072)=V transposed.
// ---------------------------------------------------------------------------
__global__ __launch_bounds__(256, 6)
void gemm_qkv(const __bf16* __restrict__ xb, const __bf16* __restrict__ Wcat,
              const float* __restrict__ bq, const float* __restrict__ bk,
              const float* __restrict__ bv,
              _Float16* __restrict__ Qh, _Float16* __restrict__ Kh, _Float16* __restrict__ Vth)
{
    __shared__ __bf16 SM[12288];         // 24 KB: A(128x64)=16KB + B(64x64)=8KB
    __bf16* AsF = SM;
    __bf16* BsF = SM + 8192;
    const int t = threadIdx.x;
    const int n0g = blockIdx.x * 64;
    const int m0  = blockIdx.y * 128;
    const int which = n0g >> 10;
    const int n_in  = n0g & 1023;

    f32x4 acc[2][4] = {};
    gemm_core64(xb, Wcat, m0, n0g, t, AsF, BsF, acc);

    const int w = t >> 6, lane = t & 63, l15 = lane & 15, quad = lane >> 4;
    const float* bias = (which == 0) ? bq : (which == 1) ? bk : bv;
    float br[4];
    #pragma unroll
    for (int ns = 0; ns < 4; ++ns) br[ns] = bias[n_in + ns*16 + l15];

    if (which == 2) {
        #pragma unroll
        for (int ms = 0; ms < 2; ++ms)
            #pragma unroll
            for (int ns = 0; ns < 4; ++ns) {
                h16x4 pk;
                #pragma unroll
                for (int rg = 0; rg < 4; ++rg) pk[rg] = (_Float16)(acc[ms][ns][rg] + br[ns]);
                *reinterpret_cast<h16x4*>(
                    &Vth[(size_t)(n_in + ns*16 + l15) * SEQ + m0 + w*32 + ms*16 + quad*4]) = pk;
            }
    } else {
        const float s = (which == 0) ? 0.1803368787f : 1.0f;  // 0.125 * log2(e)
        _Float16* C = (which == 0) ? Qh : Kh;
        __syncthreads();   // all waves done with staging LDS
        _Float16* tile = (_Float16*)SM + w * 32 * LDP;   // per-wave 32x72 region
        #pragma unroll
        for (int ms = 0; ms < 2; ++ms)
            #pragma unroll
            for (int ns = 0; ns < 4; ++ns)
                #pragma unroll
                for (int rg = 0; rg < 4; ++rg)
                    tile[(ms*16 + quad*4 + rg) * LDP + ns*16 + l15] =
                        (_Float16)((acc[ms][ns][rg] + br[ns]) * s);
        asm volatile("s_waitcnt lgkmcnt(0)" ::: "memory");   // same-wave drain
        const int er = lane >> 3, ec = (lane & 7) * 8;
        #pragma unroll
        for (int p = 0; p < 4; ++p) {
            const h16x8 v = *reinterpret_cast<const h16x8*>(&tile[(er + p*8) * LDP + ec]);
            *reinterpret_cast<h16x8*>(
                &C[(size_t)(m0 + w*32 + er + p*8) * DMODEL + n_in + ec]) = v;
        }
    }
}

// ---------------------------------------------------------------------------
// Output projection, V12: 64x64 tiles. Grid (16,64) = 1024 blocks = exactly
// 4/CU (LDS 16KB*4=64KB), 16 waves/CU vs the old 128x64 grid's 8.
// ---------------------------------------------------------------------------
__global__ __launch_bounds__(256, 4)
void gemm_out(const __bf16* __restrict__ Ob, const __bf16* __restrict__ Wob,
              const float* __restrict__ bo, float* __restrict__ out)
{
    __shared__ __bf16 AsF[64*64];
    __shared__ __bf16 BsF[64*64];
    const int t = threadIdx.x;
    const int n0 = blockIdx.x * 64;
    const int m0 = blockIdx.y * 64;
    const int w = t >> 6, lane = t & 63, l15 = lane & 15, quad = lane >> 4;
    const int lr = lane >> 3, lc = lane & 7;

    f32x4 acc[4] = {};                   // wave rows w*16..w*16+15, 64 cols
    for (int k0 = 0; k0 < DMODEL; k0 += 64) {
        __syncthreads();
        #pragma unroll
        for (int p = 0; p < 2; ++p) {
            const int n = w*2 + p;
            const int r = n*8 + lr;
            const int cl = lc ^ (r & 7);
            GLOAD_LDS16(&Ob [(size_t)(m0 + r) * DMODEL + k0 + cl*8], &AsF[n*512]);
            GLOAD_LDS16(&Wob[(size_t)(n0 + r) * DMODEL + k0 + cl*8], &BsF[n*512]);
        }
        __syncthreads();
        #pragma unroll
        for (int kb = 0; kb < 2; ++kb) {
            const int phys = ((kb*4 + quad) ^ (l15 & 7)) * 8;
            const bf16x8 af = *reinterpret_cast<const bf16x8*>(&AsF[(w*16 + l15)*64 + phys]);
            #pragma unroll
            for (int ns = 0; ns < 4; ++ns) {
                const bf16x8 bfr = *reinterpret_cast<const bf16x8*>(&BsF[(ns*16 + l15)*64 + phys]);
                acc[ns] = __builtin_amdgcn_mfma_f32_16x16x32_bf16(af, bfr, acc[ns], 0, 0, 0);
            }
        }
    }

    float br[4];
    #pragma unroll
    for (int ns = 0; ns < 4; ++ns) br[ns] = bo[n0 + ns*16 + l15];
    #pragma unroll
    for (int ns = 0; ns < 4; ++ns)
        #pragma unroll
        for (int rg = 0; rg < 4; ++rg)
            out[(size_t)(m0 + w*16 + quad*4 + rg) * DMODEL + n0 + ns*16 + l15] =
                acc[ns][rg] + br[ns];
}

// ---------------------------------------------------------------------------
// Causal flash attention, V6 exact (verified best: attn 68us): equal 22-tile
// units, 768 blocks = exactly 3/CU one uniform round, 2-buffer DMA LDS with
// one __syncthreads per tile. (V7 counted-vmcnt, V8/V9/V10 occupancy pushes,
// V11 setprio: all null or negative — this structure is the plateau.)
// ---------------------------------------------------------------------------
__global__ __launch_bounds__(256, 3)
void attn_mfma(const _Float16* __restrict__ Q, const _Float16* __restrict__ K,
               const _Float16* __restrict__ Vt, __bf16* __restrict__ O,
               _Float16* __restrict__ partA, _Float16* __restrict__ partB,
               float* __restrict__ lpart)
{
    __shared__ _Float16 KsF[2][64*64];   // [key][d], chunk-XOR swizzled (DMA)
    __shared__ _Float16 VsF[2][64*64];   // [d][key], chunk-XOR swizzled (DMA)

    const int t = threadIdx.x;
    const int w = t >> 6;
    const int lane = t & 63, l15 = lane & 15, quad = lane >> 4;
    const int lr = lane >> 3, lc = lane & 7;
    const int h = blockIdx.y;
    const int u = blockIdx.x;

    const int cl = lc ^ lr;
    const int rA = (w*2 + 0)*8 + lr, rB = (w*2 + 1)*8 + lr;
    const int dA = (w*2 + 0)*512,   dB = (w*2 + 1)*512;
    const h16x4 vone = {(_Float16)1.f, (_Float16)1.f, (_Float16)1.f, (_Float16)1.f};

    int g = u * 22;                      // global tile cursor
    const int gend = g + 22;
    int qt = 0;
    while ((qt + 1) * (qt + 2) <= g) ++qt;   // S(qt) <= g < S(qt+1)

    while (g < gend) {
        const int S = qt * (qt + 1);
        const int rowlen = 2*qt + 2;
        const int ts = g - S;
        const int rem = gend - S;
        const int te = (rowlen < rem) ? rowlen : rem;    // local tile range [ts,te)
        const int s0 = qt*128 + w*16;    // slice0 row base
        const int s1 = s0 + 64;          // slice1 row base

        // Q B-frags (x32: lane n=q=l15 holds d=quad*8+j), both slices.
        h16x8 bq8[2][2];
        #pragma unroll
        for (int kb = 0; kb < 2; ++kb) {
            bq8[0][kb] = *reinterpret_cast<const h16x8*>(
                &Q[(size_t)(s0 + l15) * DMODEL + h*DK + kb*32 + quad*8]);
            bq8[1][kb] = *reinterpret_cast<const h16x8*>(
                &Q[(size_t)(s1 + l15) * DMODEL + h*DK + kb*32 + quad*8]);
        }

        // staging sources for this segment (XOR-pre-swizzled; dest linear)
        const _Float16* kpA = &K [(size_t)(ts*64 + rA) * DMODEL + h*DK + cl*8];
        const _Float16* kpB = &K [(size_t)(ts*64 + rB) * DMODEL + h*DK + cl*8];
        const _Float16* vpA = &Vt[(size_t)(h*DK + rA) * SEQ + ts*64 + cl*8];
        const _Float16* vpB = &Vt[(size_t)(h*DK + rB) * SEQ + ts*64 + cl*8];

#define STAGE_KV(bi) do {                                     \
        GLOAD_LDS16(kpA, &KsF[bi][dA]);                       \
        GLOAD_LDS16(kpB, &KsF[bi][dB]);                       \
        GLOAD_LDS16(vpA, &VsF[bi][dA]);                       \
        GLOAD_LDS16(vpB, &VsF[bi][dB]);                       \
        kpA += (size_t)64*DMODEL; kpB += (size_t)64*DMODEL;   \
        vpA += 64; vpB += 64; } while (0)

        f32x4 acc[2][4] = {};        // [slice][dsub]; C: col=d=l15, row=q=quad*4+rg
        f32x4 accl[2] = {};          // denom rowsums via ones-MFMA

        STAGE_KV(0);                 // prologue: stage tile ts into buffer 0
        __syncthreads();             // drains prologue DMA + barrier

        int pbuf = 0;
        for (int tk = ts; tk < te; ++tk, pbuf ^= 1) {
            if (tk + 1 < te) STAGE_KV(pbuf ^ 1);   // issue next tile's DMA first

            const int j0 = tk * 64;
            const bool act0 = (j0 <= s0 + 15);   // slice0 still in causal range
            const bool msk0 = (j0 + 63 > s0);    // wave-uniform
            const bool msk1 = (j0 + 63 > s1);    // wave-uniform
            const int rel0 = s0 - j0 + l15;
            const int rel1 = s1 - j0 + l15;

            // ---- S^T = K . Q^T (x32); K A-frags shared by both slices ----
            h16x4 ap[2][4];
            #pragma unroll
            for (int st = 0; st < 4; ++st) {
                const h16x8 ak0 = *reinterpret_cast<const h16x8*>(
                    &KsF[pbuf][(st*16 + l15)*64 + ((quad ^ (l15 & 7)))*8]);
                const h16x8 ak1 = *reinterpret_cast<const h16x8*>(
                    &KsF[pbuf][(st*16 + l15)*64 + (((4 + quad) ^ (l15 & 7)))*8]);
                // slice 1 (always active)
                {
                    f32x4 cc = {0.f, 0.f, 0.f, 0.f};
                    cc = __builtin_amdgcn_mfma_f32_16x16x32_f16(ak0, bq8[1][0], cc, 0, 0, 0);
                    cc = __builtin_amdgcn_mfma_f32_16x16x32_f16(ak1, bq8[1][1], cc, 0, 0, 0);
                    float pv[4];
                    if (msk1) {
                        #pragma unroll
                        for (int rg = 0; rg < 4; ++rg) {
                            const float e = EXP2R(cc[rg]);
                            pv[rg] = (st*16 + quad*4 + rg > rel1) ? 0.f : e;
                        }
                    } else {
                        #pragma unroll
                        for (int rg = 0; rg < 4; ++rg) pv[rg] = EXP2R(cc[rg]);
                    }
                    const h16x2 lo = cvt_pk_h16(pv[0], pv[1]);
                    const h16x2 hi = cvt_pk_h16(pv[2], pv[3]);
                    ap[1][st] = (h16x4){lo[0], lo[1], hi[0], hi[1]};
                    accl[1] = __builtin_amdgcn_mfma_f32_16x16x16f16(ap[1][st], vone, accl[1], 0, 0, 0);
                }
                // slice 0
                if (act0) {
                    f32x4 cc = {0.f, 0.f, 0.f, 0.f};
                    cc = __builtin_amdgcn_mfma_f32_16x16x32_f16(ak0, bq8[0][0], cc, 0, 0, 0);
                    cc = __builtin_amdgcn_mfma_f32_16x16x32_f16(ak1, bq8[0][1], cc, 0, 0, 0);
                    float pv[4];
                    if (msk0) {
                        #pragma unroll
                        for (int rg = 0; rg < 4; ++rg) {
                            const float e = EXP2R(cc[rg]);
                            pv[rg] = (st*16 + quad*4 + rg > rel0) ? 0.f : e;
                        }
                    } else {
                        #pragma unroll
                        for (int rg = 0; rg < 4; ++rg) pv[rg] = EXP2R(cc[rg]);
                    }
                    const h16x2 lo = cvt_pk_h16(pv[0], pv[1]);
                    const h16x2 hi = cvt_pk_h16(pv[2], pv[3]);
                    ap[0][st] = (h16x4){lo[0], lo[1], hi[0], hi[1]};
                    accl[0] = __builtin_amdgcn_mfma_f32_16x16x16f16(ap[0][st], vone, accl[0], 0, 0, 0);
                }
            }

            // ---- O^ += P . V (x16); V B-frags shared by both slices ----
            #pragma unroll
            for (int ds_ = 0; ds_ < 4; ++ds_) {
                #pragma unroll
                for (int st = 0; st < 4; ++st) {
                    const h16x4 bv = *reinterpret_cast<const h16x4*>(
                        &VsF[pbuf][(ds_*16 + l15)*64 +
                                   (((st*2 + (quad >> 1)) ^ (l15 & 7)))*8 + (quad & 1)*4]);
                    acc[1][ds_] = __builtin_amdgcn_mfma_f32_16x16x16f16(ap[1][st], bv, acc[1][ds_], 0, 0, 0);
                    if (act0)
                        acc[0][ds_] = __builtin_amdgcn_mfma_f32_16x16x16f16(ap[0][st], bv, acc[0][ds_], 0, 0, 0);
                }
            }
            __syncthreads();   // readers of pbuf done + next-tile DMA drained
        }
#undef STAGE_KV

        // ---- segment epilogue ----
        if (ts == 0 && te == rowlen) {
            // full row in this chunk: normalize and write bf16 O
            #pragma unroll
            for (int s = 0; s < 2; ++s) {
                const int base = s ? s1 : s0;
                #pragma unroll
                for (int rg = 0; rg < 4; ++rg) {
                    const float inv = 1.0f / accl[s][rg];
                    const size_t row = (size_t)(base + quad*4 + rg) * DMODEL + h * DK;
                    #pragma unroll
                    for (int ds_ = 0; ds_ < 4; ++ds_)
                        O[row + ds_*16 + l15] = (__bf16)(acc[s][ds_][rg] * inv);
                }
            }
        } else {
            const int side = (g == u*22) ? 0 : 1;   // first segment of chunk?
            const int slot = (h*48 + u)*2 + side;
            _Float16* p = (slot < 1024) ? partA + (size_t)slot * 8192
                                        : partB + (size_t)(slot - 1024) * 8192;
            #pragma unroll
            for (int s = 0; s < 2; ++s) {
                #pragma unroll
                for (int rg = 0; rg < 4; ++rg) {
                    const int lrow = s*64 + w*16 + quad*4 + rg;
                    #pragma unroll
                    for (int ds_ = 0; ds_ < 4; ++ds_)
                        p[lrow*64 + ds_*16 + l15] = (_Float16)acc[s][ds_][rg];
                    if (l15 == 0) lpart[(size_t)slot*128 + lrow] = accl[s][rg];
                }
            }
        }
        g = S + te;
        ++qt;
    }
}

// ---------------------------------------------------------------------------
// Combine fp16 partials for rows split across chunks: O = sum p / sum l.
// Row qt spans chunks c0..c1; side(c) = (22c >= S(qt)) ? 0 : 1.
// ---------------------------------------------------------------------------
__global__ __launch_bounds__(256)
void attn_combine(const _Float16* __restrict__ partA, const _Float16* __restrict__ partB,
                  const float* __restrict__ lpart, __bf16* __restrict__ O)
{
    const int t = threadIdx.x;
    const int qt = blockIdx.x;           // 0..31
    const int h  = blockIdx.y;
    const int S = qt*(qt+1);
    const int rowlen = 2*qt + 2;
    const int c0 = S / 22;
    const int c1 = (S + rowlen - 1) / 22;
    if (c0 == c1) return;                // finalized in attn_mfma
    const int r  = t >> 1;               // 0..127 local row
    const int d0 = (t & 1) * 32;

    float a[4][8] = {};
    float l = 0.f;
    for (int c = c0; c <= c1; ++c) {
        const int side = (22*c >= S) ? 0 : 1;
        const int sl = (h*48 + c)*2 + side;
        const _Float16* pc = (sl < 1024) ? partA + (size_t)sl * 8192
                                         : partB + (size_t)(sl - 1024) * 8192;
        l += lpart[(size_t)sl*128 + r];
        #pragma unroll
        for (int i = 0; i < 4; ++i) {
            const h16x8 v = *reinterpret_cast<const h16x8*>(&pc[r*64 + d0 + i*8]);
            #pragma unroll
            for (int j = 0; j < 8; ++j) a[i][j] += (float)v[j];
        }
    }
    const float inv = 1.0f / l;
    const size_t grow = (size_t)(qt*128 + r) * DMODEL + h*64 + d0;
    #pragma unroll
    for (int i = 0; i < 4; ++i) {
        bf16x8 pk;
        #pragma unroll
        for (int j = 0; j < 8; ++j) pk[j] = (__bf16)(a[i][j] * inv);
        *reinterpret_cast<bf16x8*>(&O[grow + i*8]) = pk;
    }
}

// ---------------------------------------------------------------------------
extern "C" void kernel_launch(void* const* d_in, const int* in_sizes, int n_in,
                              void* d_out, int out_size, void* d_ws, size_t ws_size,
                              hipStream_t stream) {
    const float* x  = (const float*)d_in[0];
    const float* Wq = (const float*)d_in[1];
    const float* bq = (const float*)d_in[2];
    const float* Wk = (const float*)d_in[3];
    const float* bk = (const float*)d_in[4];
    const float* Wv = (const float*)d_in[5];
    const float* bv = (const float*)d_in[6];
    const float* Wo = (const float*)d_in[7];
    const float* bo = (const float*)d_in[8];
    float* out = (float*)d_out;

    const size_t M1 = 1u << 20;
    __bf16* base = (__bf16*)d_ws;
    __bf16*    xb   = base;                          // 4M bf16 (free after gemm_qkv)
    __bf16*    Wcat = base + 4*M1;                   // Wq|Wk|Wv (free after gemm_qkv)
    __bf16*    Wob  = base + 7*M1;                   // 1M bf16
    _Float16*  Qh   = (_Float16*)(base + 8*M1);      // 4M fp16 each
    _Float16*  Kh   = (_Float16*)(base + 12*M1);
    _Float16*  Vth  = (_Float16*)(base + 16*M1);
    __bf16*    Ob   = base + 20*M1;                  // 4M bf16
    // fp16 partials: slots 0..1023 in d_out (16 MB), 1024..1535 in xb (8 MB)
    _Float16*  partA = (_Float16*)out;
    _Float16*  partB = (_Float16*)xb;
    // per-slot row sums: 1536*128 fp32 = 786 KB in the Wcat region
    float*     lpart = (float*)Wcat;

    cvt_all<<<4096, 256, 0, stream>>>(x, Wq, Wk, Wv, Wo, base);
    gemm_qkv<<<dim3(48, 32), 256, 0, stream>>>(xb, Wcat, bq, bk, bv, Qh, Kh, Vth);
    attn_mfma<<<dim3(48, NH), 256, 0, stream>>>(Qh, Kh, Vth, Ob, partA, partB, lpart);
    attn_combine<<<dim3(32, NH), 256, 0, stream>>>(partA, partB, lpart, Ob);
    gemm_out<<<dim3(16, 64), 256, 0, stream>>>(Ob, Wob, bo, out);
}

// Round 13
// 207.540 us; speedup vs baseline: 1.0950x; 1.0950x over previous
//
#include <hip/hip_runtime.h>
#include <math.h>

#define SEQ 4096
#define DMODEL 1024
#define NH 16
#define DK 64
#define LDP 72   // padded LDS row (16-bit elems): conflict-free b64/b128 frag reads

typedef __bf16    bf16x8 __attribute__((ext_vector_type(8)));
typedef float     f32x4  __attribute__((ext_vector_type(4)));
typedef __fp16    fp16x2 __attribute__((ext_vector_type(2)));
typedef _Float16  h16x2  __attribute__((ext_vector_type(2)));
typedef _Float16  h16x4  __attribute__((ext_vector_type(4)));
typedef _Float16  h16x8  __attribute__((ext_vector_type(8)));

// global->LDS DMA, 16 B per lane; LDS dest = uniform base + lane*16 (no pad!)
#define GLOAD_LDS16(g, l) __builtin_amdgcn_global_load_lds(                     \
    (const __attribute__((address_space(1))) unsigned int*)(g),                 \
    (__attribute__((address_space(3))) unsigned int*)(l), 16, 0, 0)

// packed f32->f16 (RTZ), re-typed to _Float16x2
__device__ __forceinline__ h16x2 cvt_pk_h16(float a, float b) {
    fp16x2 r = __builtin_amdgcn_cvt_pkrtz(a, b);
    return __builtin_bit_cast(h16x2, r);
}

// raw v_exp_f32 (no denormal-guard expansion; inputs bounded)
#define EXP2R(x) __builtin_amdgcn_exp2f(x)

// ---------------------------------------------------------------------------
// Convert x (4M) + Wq/Wk/Wv/Wo (1M each) fp32 -> bf16 into contiguous ws.
// ---------------------------------------------------------------------------
__global__ __launch_bounds__(256)
void cvt_all(const float* __restrict__ x, const float* __restrict__ Wq,
             const float* __restrict__ Wk, const float* __restrict__ Wv,
             const float* __restrict__ Wo, __bf16* __restrict__ dst)
{
    const size_t M1 = 1u << 20;
    const size_t e = ((size_t)blockIdx.x * 256 + threadIdx.x) * 8;
    const float* src; size_t off;
    if      (e < 4*M1) { src = x;  off = e;        }
    else if (e < 5*M1) { src = Wq; off = e - 4*M1; }
    else if (e < 6*M1) { src = Wk; off = e - 5*M1; }
    else if (e < 7*M1) { src = Wv; off = e - 6*M1; }
    else               { src = Wo; off = e - 7*M1; }
    const float4 f0 = *reinterpret_cast<const float4*>(&src[off]);
    const float4 f1 = *reinterpret_cast<const float4*>(&src[off + 4]);
    bf16x8 pk;
    pk[0]=(__bf16)f0.x; pk[1]=(__bf16)f0.y; pk[2]=(__bf16)f0.z; pk[3]=(__bf16)f0.w;
    pk[4]=(__bf16)f1.x; pk[5]=(__bf16)f1.y; pk[6]=(__bf16)f1.z; pk[7]=(__bf16)f1.w;
    *reinterpret_cast<bf16x8*>(&dst[e]) = pk;
}

// ---------------------------------------------------------------------------
// 128x128 GEMM core with global_load_lds staging (XOR chunk swizzle).
// ---------------------------------------------------------------------------
__device__ __forceinline__ void gemm_core128(const __bf16* __restrict__ A,
                                             const __bf16* __restrict__ W,
                                             int m0, int n0, int t,
                                             __bf16* AsF, __bf16* BsF,
                                             f32x4 acc[4][4])
{
    const int w = t >> 6, lane = t & 63, l15 = lane & 15, quad = lane >> 4;
    const int wm = (w & 1) * 64, wn = (w >> 1) * 64;
    const int lr = lane >> 3, lc = lane & 7;
    for (int k0 = 0; k0 < DMODEL; k0 += 64) {
        __syncthreads();
        #pragma unroll
        for (int p = 0; p < 4; ++p) {
            const int n = w*4 + p;
            const int r = n*8 + lr;
            const int cl = lc ^ (r & 7);
            GLOAD_LDS16(&A[(size_t)(m0 + r) * DMODEL + k0 + cl*8], &AsF[n*512]);
            GLOAD_LDS16(&W[(size_t)(n0 + r) * DMODEL + k0 + cl*8], &BsF[n*512]);
        }
        __syncthreads();
        #pragma unroll
        for (int kb = 0; kb < 2; ++kb) {
            const int phys = ((kb*4 + quad) ^ (l15 & 7)) * 8;
            bf16x8 af[4], bfr[4];
            #pragma unroll
            for (int i = 0; i < 4; ++i) {
                af[i]  = *reinterpret_cast<const bf16x8*>(&AsF[(wm + i*16 + l15)*64 + phys]);
                bfr[i] = *reinterpret_cast<const bf16x8*>(&BsF[(wn + i*16 + l15)*64 + phys]);
            }
            #pragma unroll
            for (int ms = 0; ms < 4; ++ms)
                #pragma unroll
                for (int ns = 0; ns < 4; ++ns)
                    acc[ms][ns] = __builtin_amdgcn_mfma_f32_16x16x32_bf16(af[ms], bfr[ns], acc[ms][ns], 0, 0, 0);
        }
    }
}

// ---------------------------------------------------------------------------
// Fused QKV projection -> fp16. [0,1024)=Q scaled 0.125*log2e; [1024,2048)=K;
// [2048,3072)=V transposed Vt[d][s]. Q/K epilogue via per-wave LDS transpose.
// ---------------------------------------------------------------------------
__global__ __launch_bounds__(256, 3)
void gemm_qkv(const __bf16* __restrict__ xb, const __bf16* __restrict__ Wcat,
              const float* __restrict__ bq, const float* __restrict__ bk,
              const float* __restrict__ bv,
              _Float16* __restrict__ Qh, _Float16* __restrict__ Kh, _Float16* __restrict__ Vth)
{
    __shared__ __bf16 SM[4*64*LDP];      // staging uses first 32 KB
    __bf16* AsF = SM;
    __bf16* BsF = SM + 8192;
    const int t = threadIdx.x;
    const int n0g = blockIdx.x * 128;
    const int m0  = blockIdx.y * 128;
    const int which = n0g >> 10;
    const int n_in  = n0g & 1023;

    f32x4 acc[4][4] = {};
    gemm_core128(xb, Wcat, m0, n0g, t, AsF, BsF, acc);

    const int w = t >> 6, lane = t & 63, l15 = lane & 15, quad = lane >> 4;
    const int wm = (w & 1) * 64, wn = (w >> 1) * 64;
    const float* bias = (which == 0) ? bq : (which == 1) ? bk : bv;
    float br[4];
    #pragma unroll
    for (int ns = 0; ns < 4; ++ns) br[ns] = bias[n_in + wn + ns*16 + l15];

    if (which == 2) {
        #pragma unroll
        for (int ms = 0; ms < 4; ++ms)
            #pragma unroll
            for (int ns = 0; ns < 4; ++ns) {
                h16x4 pk;
                #pragma unroll
                for (int rg = 0; rg < 4; ++rg) pk[rg] = (_Float16)(acc[ms][ns][rg] + br[ns]);
                *reinterpret_cast<h16x4*>(
                    &Vth[(size_t)(n_in + wn + ns*16 + l15) * SEQ + m0 + wm + ms*16 + quad*4]) = pk;
            }
    } else {
        const float s = (which == 0) ? 0.1803368787f : 1.0f;  // 0.125 * log2(e)
        _Float16* C = (which == 0) ? Qh : Kh;
        __syncthreads();   // all waves done with staging LDS
        _Float16* tile = (_Float16*)SM + w * 64 * LDP;   // per-wave 64x72 region
        #pragma unroll
        for (int ms = 0; ms < 4; ++ms)
            #pragma unroll
            for (int ns = 0; ns < 4; ++ns)
                #pragma unroll
                for (int rg = 0; rg < 4; ++rg)
                    tile[(ms*16 + quad*4 + rg) * LDP + ns*16 + l15] =
                        (_Float16)((acc[ms][ns][rg] + br[ns]) * s);
        asm volatile("s_waitcnt lgkmcnt(0)" ::: "memory");   // same-wave drain
        const int er = lane >> 3, ec = (lane & 7) * 8;
        #pragma unroll
        for (int p = 0; p < 8; ++p) {
            const h16x8 v = *reinterpret_cast<const h16x8*>(&tile[(er + p*8) * LDP + ec]);
            *reinterpret_cast<h16x8*>(
                &C[(size_t)(m0 + wm + er + p*8) * DMODEL + n_in + wn + ec]) = v;
        }
    }
}

// ---------------------------------------------------------------------------
// 128x64 GEMM core with DMA staging, for the output projection.
// ---------------------------------------------------------------------------
__device__ __forceinline__ void gemm_core64(const __bf16* __restrict__ A,
                                            const __bf16* __restrict__ W,
                                            int m0, int n0, int t,
                                            __bf16* AsF, __bf16* BsF,
                                            f32x4 acc[2][4])
{
    const int w = t >> 6, lane = t & 63, l15 = lane & 15, quad = lane >> 4;
    const int lr = lane >> 3, lc = lane & 7;
    for (int k0 = 0; k0 < DMODEL; k0 += 64) {
        __syncthreads();
        #pragma unroll
        for (int p = 0; p < 4; ++p) {
            const int n = w*4 + p;
            const int r = n*8 + lr;
            const int cl = lc ^ (r & 7);
            GLOAD_LDS16(&A[(size_t)(m0 + r) * DMODEL + k0 + cl*8], &AsF[n*512]);
        }
        #pragma unroll
        for (int p = 0; p < 2; ++p) {
            const int n = w*2 + p;
            const int r = n*8 + lr;
            const int cl = lc ^ (r & 7);
            GLOAD_LDS16(&W[(size_t)(n0 + r) * DMODEL + k0 + cl*8], &BsF[n*512]);
        }
        __syncthreads();
        #pragma unroll
        for (int kb = 0; kb < 2; ++kb) {
            const int phys = ((kb*4 + quad) ^ (l15 & 7)) * 8;
            bf16x8 af0 = *reinterpret_cast<const bf16x8*>(&AsF[(w*32 + l15)*64 + phys]);
            bf16x8 af1 = *reinterpret_cast<const bf16x8*>(&AsF[(w*32 + 16 + l15)*64 + phys]);
            #pragma unroll
            for (int ns = 0; ns < 4; ++ns) {
                const bf16x8 bfr = *reinterpret_cast<const bf16x8*>(&BsF[(ns*16 + l15)*64 + phys]);
                acc[0][ns] = __builtin_amdgcn_mfma_f32_16x16x32_bf16(af0, bfr, acc[0][ns], 0, 0, 0);
                acc[1][ns] = __builtin_amdgcn_mfma_f32_16x16x32_bf16(af1, bfr, acc[1][ns], 0, 0, 0);
            }
        }
    }
}

__global__ __launch_bounds__(256, 4)
void gemm_out(const __bf16* __restrict__ Ob, const __bf16* __restrict__ Wob,
              const float* __restrict__ bo, float* __restrict__ out)
{
    __shared__ __bf16 AsF[128*64];
    __shared__ __bf16 BsF[64*64];
    const int t = threadIdx.x;
    const int n0 = blockIdx.x * 64;
    const int m0 = blockIdx.y * 128;

    f32x4 acc[2][4] = {};
    gemm_core64(Ob, Wob, m0, n0, t, AsF, BsF, acc);

    const int lane = t & 63, l15 = lane & 15, quad = lane >> 4, w = t >> 6;
    float br[4];
    #pragma unroll
    for (int ns = 0; ns < 4; ++ns) br[ns] = bo[n0 + ns*16 + l15];
    #pragma unroll
    for (int ms = 0; ms < 2; ++ms)
        #pragma unroll
        for (int ns = 0; ns < 4; ++ns)
            #pragma unroll
            for (int rg = 0; rg < 4; ++rg)
                out[(size_t)(m0 + w*32 + ms*16 + quad*4 + rg) * DMODEL + n0 + ns*16 + l15] =
                    acc[ms][ns][rg] + br[ns];
}

// ---------------------------------------------------------------------------
// Causal flash attention, V6 exact (verified best: attn 68us, total 205.8us):
// equal 22-tile units, 768 blocks = exactly 3/CU one uniform round, 2-buffer
// DMA LDS with one __syncthreads per tile, raw exp2, hoisted causal mask,
// ones-MFMA denominator, packed f32->f16. (V7 counted-vmcnt, V8/V9/V10
// occupancy variants, V11 setprio, V12 small GEMM tiles: all null/negative.)
// ---------------------------------------------------------------------------
__global__ __launch_bounds__(256, 3)
void attn_mfma(const _Float16* __restrict__ Q, const _Float16* __restrict__ K,
               const _Float16* __restrict__ Vt, __bf16* __restrict__ O,
               _Float16* __restrict__ partA, _Float16* __restrict__ partB,
               float* __restrict__ lpart)
{
    __shared__ _Float16 KsF[2][64*64];   // [key][d], chunk-XOR swizzled (DMA)
    __shared__ _Float16 VsF[2][64*64];   // [d][key], chunk-XOR swizzled (DMA)

    const int t = threadIdx.x;
    const int w = t >> 6;
    const int lane = t & 63, l15 = lane & 15, quad = lane >> 4;
    const int lr = lane >> 3, lc = lane & 7;
    const int h = blockIdx.y;
    const int u = blockIdx.x;

    const int cl = lc ^ lr;
    const int rA = (w*2 + 0)*8 + lr, rB = (w*2 + 1)*8 + lr;
    const int dA = (w*2 + 0)*512,   dB = (w*2 + 1)*512;
    const h16x4 vone = {(_Float16)1.f, (_Float16)1.f, (_Float16)1.f, (_Float16)1.f};

    int g = u * 22;                      // global tile cursor
    const int gend = g + 22;
    int qt = 0;
    while ((qt + 1) * (qt + 2) <= g) ++qt;   // S(qt) <= g < S(qt+1)

    while (g < gend) {
        const int S = qt * (qt + 1);
        const int rowlen = 2*qt + 2;
        const int ts = g - S;
        const int rem = gend - S;
        const int te = (rowlen < rem) ? rowlen : rem;    // local tile range [ts,te)
        const int s0 = qt*128 + w*16;    // slice0 row base
        const int s1 = s0 + 64;          // slice1 row base

        // Q B-frags (x32: lane n=q=l15 holds d=quad*8+j), both slices.
        h16x8 bq8[2][2];
        #pragma unroll
        for (int kb = 0; kb < 2; ++kb) {
            bq8[0][kb] = *reinterpret_cast<const h16x8*>(
                &Q[(size_t)(s0 + l15) * DMODEL + h*DK + kb*32 + quad*8]);
            bq8[1][kb] = *reinterpret_cast<const h16x8*>(
                &Q[(size_t)(s1 + l15) * DMODEL + h*DK + kb*32 + quad*8]);
        }

        // staging sources for this segment (XOR-pre-swizzled; dest linear)
        const _Float16* kpA = &K [(size_t)(ts*64 + rA) * DMODEL + h*DK + cl*8];
        const _Float16* kpB = &K [(size_t)(ts*64 + rB) * DMODEL + h*DK + cl*8];
        const _Float16* vpA = &Vt[(size_t)(h*DK + rA) * SEQ + ts*64 + cl*8];
        const _Float16* vpB = &Vt[(size_t)(h*DK + rB) * SEQ + ts*64 + cl*8];

#define STAGE_KV(bi) do {                                     \
        GLOAD_LDS16(kpA, &KsF[bi][dA]);                       \
        GLOAD_LDS16(kpB, &KsF[bi][dB]);                       \
        GLOAD_LDS16(vpA, &VsF[bi][dA]);                       \
        GLOAD_LDS16(vpB, &VsF[bi][dB]);                       \
        kpA += (size_t)64*DMODEL; kpB += (size_t)64*DMODEL;   \
        vpA += 64; vpB += 64; } while (0)

        f32x4 acc[2][4] = {};        // [slice][dsub]; C: col=d=l15, row=q=quad*4+rg
        f32x4 accl[2] = {};          // denom rowsums via ones-MFMA

        STAGE_KV(0);                 // prologue: stage tile ts into buffer 0
        __syncthreads();             // drains prologue DMA + barrier

        int pbuf = 0;
        for (int tk = ts; tk < te; ++tk, pbuf ^= 1) {
            if (tk + 1 < te) STAGE_KV(pbuf ^ 1);   // issue next tile's DMA first

            const int j0 = tk * 64;
            const bool act0 = (j0 <= s0 + 15);   // slice0 still in causal range
            const bool msk0 = (j0 + 63 > s0);    // wave-uniform
            const bool msk1 = (j0 + 63 > s1);    // wave-uniform
            const int rel0 = s0 - j0 + l15;
            const int rel1 = s1 - j0 + l15;

            // ---- S^T = K . Q^T (x32); K A-frags shared by both slices ----
            h16x4 ap[2][4];
            #pragma unroll
            for (int st = 0; st < 4; ++st) {
                const h16x8 ak0 = *reinterpret_cast<const h16x8*>(
                    &KsF[pbuf][(st*16 + l15)*64 + ((quad ^ (l15 & 7)))*8]);
                const h16x8 ak1 = *reinterpret_cast<const h16x8*>(
                    &KsF[pbuf][(st*16 + l15)*64 + (((4 + quad) ^ (l15 & 7)))*8]);
                // slice 1 (always active)
                {
                    f32x4 cc = {0.f, 0.f, 0.f, 0.f};
                    cc = __builtin_amdgcn_mfma_f32_16x16x32_f16(ak0, bq8[1][0], cc, 0, 0, 0);
                    cc = __builtin_amdgcn_mfma_f32_16x16x32_f16(ak1, bq8[1][1], cc, 0, 0, 0);
                    float pv[4];
                    if (msk1) {
                        #pragma unroll
                        for (int rg = 0; rg < 4; ++rg) {
                            const float e = EXP2R(cc[rg]);
                            pv[rg] = (st*16 + quad*4 + rg > rel1) ? 0.f : e;
                        }
                    } else {
                        #pragma unroll
                        for (int rg = 0; rg < 4; ++rg) pv[rg] = EXP2R(cc[rg]);
                    }
                    const h16x2 lo = cvt_pk_h16(pv[0], pv[1]);
                    const h16x2 hi = cvt_pk_h16(pv[2], pv[3]);
                    ap[1][st] = (h16x4){lo[0], lo[1], hi[0], hi[1]};
                    accl[1] = __builtin_amdgcn_mfma_f32_16x16x16f16(ap[1][st], vone, accl[1], 0, 0, 0);
                }
                // slice 0
                if (act0) {
                    f32x4 cc = {0.f, 0.f, 0.f, 0.f};
                    cc = __builtin_amdgcn_mfma_f32_16x16x32_f16(ak0, bq8[0][0], cc, 0, 0, 0);
                    cc = __builtin_amdgcn_mfma_f32_16x16x32_f16(ak1, bq8[0][1], cc, 0, 0, 0);
                    float pv[4];
                    if (msk0) {
                        #pragma unroll
                        for (int rg = 0; rg < 4; ++rg) {
                            const float e = EXP2R(cc[rg]);
                            pv[rg] = (st*16 + quad*4 + rg > rel0) ? 0.f : e;
                        }
                    } else {
                        #pragma unroll
                        for (int rg = 0; rg < 4; ++rg) pv[rg] = EXP2R(cc[rg]);
                    }
                    const h16x2 lo = cvt_pk_h16(pv[0], pv[1]);
                    const h16x2 hi = cvt_pk_h16(pv[2], pv[3]);
                    ap[0][st] = (h16x4){lo[0], lo[1], hi[0], hi[1]};
                    accl[0] = __builtin_amdgcn_mfma_f32_16x16x16f16(ap[0][st], vone, accl[0], 0, 0, 0);
                }
            }

            // ---- O^ += P . V (x16); V B-frags shared by both slices ----
            #pragma unroll
            for (int ds_ = 0; ds_ < 4; ++ds_) {
                #pragma unroll
                for (int st = 0; st < 4; ++st) {
                    const h16x4 bv = *reinterpret_cast<const h16x4*>(
                        &VsF[pbuf][(ds_*16 + l15)*64 +
                                   (((st*2 + (quad >> 1)) ^ (l15 & 7)))*8 + (quad & 1)*4]);
                    acc[1][ds_] = __builtin_amdgcn_mfma_f32_16x16x16f16(ap[1][st], bv, acc[1][ds_], 0, 0, 0);
                    if (act0)
                        acc[0][ds_] = __builtin_amdgcn_mfma_f32_16x16x16f16(ap[0][st], bv, acc[0][ds_], 0, 0, 0);
                }
            }
            __syncthreads();   // readers of pbuf done + next-tile DMA drained
        }
#undef STAGE_KV

        // ---- segment epilogue ----
        if (ts == 0 && te == rowlen) {
            // full row in this chunk: normalize and write bf16 O
            #pragma unroll
            for (int s = 0; s < 2; ++s) {
                const int base = s ? s1 : s0;
                #pragma unroll
                for (int rg = 0; rg < 4; ++rg) {
                    const float inv = 1.0f / accl[s][rg];
                    const size_t row = (size_t)(base + quad*4 + rg) * DMODEL + h * DK;
                    #pragma unroll
                    for (int ds_ = 0; ds_ < 4; ++ds_)
                        O[row + ds_*16 + l15] = (__bf16)(acc[s][ds_][rg] * inv);
                }
            }
        } else {
            const int side = (g == u*22) ? 0 : 1;   // first segment of chunk?
            const int slot = (h*48 + u)*2 + side;
            _Float16* p = (slot < 1024) ? partA + (size_t)slot * 8192
                                        : partB + (size_t)(slot - 1024) * 8192;
            #pragma unroll
            for (int s = 0; s < 2; ++s) {
                #pragma unroll
                for (int rg = 0; rg < 4; ++rg) {
                    const int lrow = s*64 + w*16 + quad*4 + rg;
                    #pragma unroll
                    for (int ds_ = 0; ds_ < 4; ++ds_)
                        p[lrow*64 + ds_*16 + l15] = (_Float16)acc[s][ds_][rg];
                    if (l15 == 0) lpart[(size_t)slot*128 + lrow] = accl[s][rg];
                }
            }
        }
        g = S + te;
        ++qt;
    }
}

// ---------------------------------------------------------------------------
// Combine fp16 partials for rows split across chunks: O = sum p / sum l.
// Row qt spans chunks c0..c1; side(c) = (22c >= S(qt)) ? 0 : 1.
// ---------------------------------------------------------------------------
__global__ __launch_bounds__(256)
void attn_combine(const _Float16* __restrict__ partA, const _Float16* __restrict__ partB,
                  const float* __restrict__ lpart, __bf16* __restrict__ O)
{
    const int t = threadIdx.x;
    const int qt = blockIdx.x;           // 0..31
    const int h  = blockIdx.y;
    const int S = qt*(qt+1);
    const int rowlen = 2*qt + 2;
    const int c0 = S / 22;
    const int c1 = (S + rowlen - 1) / 22;
    if (c0 == c1) return;                // finalized in attn_mfma
    const int r  = t >> 1;               // 0..127 local row
    const int d0 = (t & 1) * 32;

    float a[4][8] = {};
    float l = 0.f;
    for (int c = c0; c <= c1; ++c) {
        const int side = (22*c >= S) ? 0 : 1;
        const int sl = (h*48 + c)*2 + side;
        const _Float16* pc = (sl < 1024) ? partA + (size_t)sl * 8192
                                         : partB + (size_t)(sl - 1024) * 8192;
        l += lpart[(size_t)sl*128 + r];
        #pragma unroll
        for (int i = 0; i < 4; ++i) {
            const h16x8 v = *reinterpret_cast<const h16x8*>(&pc[r*64 + d0 + i*8]);
            #pragma unroll
            for (int j = 0; j < 8; ++j) a[i][j] += (float)v[j];
        }
    }
    const float inv = 1.0f / l;
    const size_t grow = (size_t)(qt*128 + r) * DMODEL + h*64 + d0;
    #pragma unroll
    for (int i = 0; i < 4; ++i) {
        bf16x8 pk;
        #pragma unroll
        for (int j = 0; j < 8; ++j) pk[j] = (__bf16)(a[i][j] * inv);
        *reinterpret_cast<bf16x8*>(&O[grow + i*8]) = pk;
    }
}

// ---------------------------------------------------------------------------
extern "C" void kernel_launch(void* const* d_in, const int* in_sizes, int n_in,
                              void* d_out, int out_size, void* d_ws, size_t ws_size,
                              hipStream_t stream) {
    const float* x  = (const float*)d_in[0];
    const float* Wq = (const float*)d_in[1];
    const float* bq = (const float*)d_in[2];
    const float* Wk = (const float*)d_in[3];
    const float* bk = (const float*)d_in[4];
    const float* Wv = (const float*)d_in[5];
    const float* bv = (const float*)d_in[6];
    const float* Wo = (const float*)d_in[7];
    const float* bo = (const float*)d_in[8];
    float* out = (float*)d_out;

    const size_t M1 = 1u << 20;
    __bf16* base = (__bf16*)d_ws;
    __bf16*    xb   = base;                          // 4M bf16 (free after gemm_qkv)
    __bf16*    Wcat = base + 4*M1;                   // Wq|Wk|Wv (free after gemm_qkv)
    __bf16*    Wob  = base + 7*M1;                   // 1M bf16
    _Float16*  Qh   = (_Float16*)(base + 8*M1);      // 4M fp16 each
    _Float16*  Kh   = (_Float16*)(base + 12*M1);
    _Float16*  Vth  = (_Float16*)(base + 16*M1);
    __bf16*    Ob   = base + 20*M1;                  // 4M bf16
    // fp16 partials: slots 0..1023 in d_out (16 MB), 1024..1535 in xb (8 MB)
    _Float16*  partA = (_Float16*)out;
    _Float16*  partB = (_Float16*)xb;
    // per-slot row sums: 1536*128 fp32 = 786 KB in the Wcat region
    float*     lpart = (float*)Wcat;

    cvt_all<<<4096, 256, 0, stream>>>(x, Wq, Wk, Wv, Wo, base);
    gemm_qkv<<<dim3(24, 32), 256, 0, stream>>>(xb, Wcat, bq, bk, bv, Qh, Kh, Vth);
    attn_mfma<<<dim3(48, NH), 256, 0, stream>>>(Qh, Kh, Vth, Ob, partA, partB, lpart);
    attn_combine<<<dim3(32, NH), 256, 0, stream>>>(partA, partB, lpart, Ob);
    gemm_out<<<dim3(16, 32), 256, 0, stream>>>(Ob, Wob, bo, out);
}

// Round 14
// 206.319 us; speedup vs baseline: 1.1015x; 1.0059x over previous
//
#include <hip/hip_runtime.h>
#include <math.h>

#define SEQ 4096
#define DMODEL 1024
#define NH 16
#define DK 64
#define LDP 72   // padded LDS row (16-bit elems): conflict-free b64/b128 frag reads

typedef __bf16    bf16x8 __attribute__((ext_vector_type(8)));
typedef float     f32x4  __attribute__((ext_vector_type(4)));
typedef __fp16    fp16x2 __attribute__((ext_vector_type(2)));
typedef _Float16  h16x2  __attribute__((ext_vector_type(2)));
typedef _Float16  h16x4  __attribute__((ext_vector_type(4)));
typedef _Float16  h16x8  __attribute__((ext_vector_type(8)));

// global->LDS DMA, 16 B per lane; LDS dest = uniform base + lane*16 (no pad!)
#define GLOAD_LDS16(g, l) __builtin_amdgcn_global_load_lds(                     \
    (const __attribute__((address_space(1))) unsigned int*)(g),                 \
    (__attribute__((address_space(3))) unsigned int*)(l), 16, 0, 0)

// packed f32->f16 (RTZ), re-typed to _Float16x2
__device__ __forceinline__ h16x2 cvt_pk_h16(float a, float b) {
    fp16x2 r = __builtin_amdgcn_cvt_pkrtz(a, b);
    return __builtin_bit_cast(h16x2, r);
}

// raw v_exp_f32 (no denormal-guard expansion; inputs bounded)
#define EXP2R(x) __builtin_amdgcn_exp2f(x)

// ---------------------------------------------------------------------------
// Convert x (4M) + Wq/Wk/Wv/Wo (1M each) fp32 -> bf16 into contiguous ws.
// ---------------------------------------------------------------------------
__global__ __launch_bounds__(256)
void cvt_all(const float* __restrict__ x, const float* __restrict__ Wq,
             const float* __restrict__ Wk, const float* __restrict__ Wv,
             const float* __restrict__ Wo, __bf16* __restrict__ dst)
{
    const size_t M1 = 1u << 20;
    const size_t e = ((size_t)blockIdx.x * 256 + threadIdx.x) * 8;
    const float* src; size_t off;
    if      (e < 4*M1) { src = x;  off = e;        }
    else if (e < 5*M1) { src = Wq; off = e - 4*M1; }
    else if (e < 6*M1) { src = Wk; off = e - 5*M1; }
    else if (e < 7*M1) { src = Wv; off = e - 6*M1; }
    else               { src = Wo; off = e - 7*M1; }
    const float4 f0 = *reinterpret_cast<const float4*>(&src[off]);
    const float4 f1 = *reinterpret_cast<const float4*>(&src[off + 4]);
    bf16x8 pk;
    pk[0]=(__bf16)f0.x; pk[1]=(__bf16)f0.y; pk[2]=(__bf16)f0.z; pk[3]=(__bf16)f0.w;
    pk[4]=(__bf16)f1.x; pk[5]=(__bf16)f1.y; pk[6]=(__bf16)f1.z; pk[7]=(__bf16)f1.w;
    *reinterpret_cast<bf16x8*>(&dst[e]) = pk;
}

// ---------------------------------------------------------------------------
// 128x128 GEMM core with global_load_lds staging (XOR chunk swizzle).
// ---------------------------------------------------------------------------
__device__ __forceinline__ void gemm_core128(const __bf16* __restrict__ A,
                                             const __bf16* __restrict__ W,
                                             int m0, int n0, int t,
                                             __bf16* AsF, __bf16* BsF,
                                             f32x4 acc[4][4])
{
    const int w = t >> 6, lane = t & 63, l15 = lane & 15, quad = lane >> 4;
    const int wm = (w & 1) * 64, wn = (w >> 1) * 64;
    const int lr = lane >> 3, lc = lane & 7;
    for (int k0 = 0; k0 < DMODEL; k0 += 64) {
        __syncthreads();
        #pragma unroll
        for (int p = 0; p < 4; ++p) {
            const int n = w*4 + p;
            const int r = n*8 + lr;
            const int cl = lc ^ (r & 7);
            GLOAD_LDS16(&A[(size_t)(m0 + r) * DMODEL + k0 + cl*8], &AsF[n*512]);
            GLOAD_LDS16(&W[(size_t)(n0 + r) * DMODEL + k0 + cl*8], &BsF[n*512]);
        }
        __syncthreads();
        #pragma unroll
        for (int kb = 0; kb < 2; ++kb) {
            const int phys = ((kb*4 + quad) ^ (l15 & 7)) * 8;
            bf16x8 af[4], bfr[4];
            #pragma unroll
            for (int i = 0; i < 4; ++i) {
                af[i]  = *reinterpret_cast<const bf16x8*>(&AsF[(wm + i*16 + l15)*64 + phys]);
                bfr[i] = *reinterpret_cast<const bf16x8*>(&BsF[(wn + i*16 + l15)*64 + phys]);
            }
            #pragma unroll
            for (int ms = 0; ms < 4; ++ms)
                #pragma unroll
                for (int ns = 0; ns < 4; ++ns)
                    acc[ms][ns] = __builtin_amdgcn_mfma_f32_16x16x32_bf16(af[ms], bfr[ns], acc[ms][ns], 0, 0, 0);
        }
    }
}

// ---------------------------------------------------------------------------
// Fused QKV projection -> fp16. [0,1024)=Q scaled 0.125*log2e; [1024,2048)=K;
// [2048,3072)=V transposed Vt[d][s]. Q/K epilogue via per-wave LDS transpose.
// ---------------------------------------------------------------------------
__global__ __launch_bounds__(256, 3)
void gemm_qkv(const __bf16* __restrict__ xb, const __bf16* __restrict__ Wcat,
              const float* __restrict__ bq, const float* __restrict__ bk,
              const float* __restrict__ bv,
              _Float16* __restrict__ Qh, _Float16* __restrict__ Kh, _Float16* __restrict__ Vth)
{
    __shared__ __bf16 SM[4*64*LDP];      // staging uses first 32 KB
    __bf16* AsF = SM;
    __bf16* BsF = SM + 8192;
    const int t = threadIdx.x;
    const int n0g = blockIdx.x * 128;
    const int m0  = blockIdx.y * 128;
    const int which = n0g >> 10;
    const int n_in  = n0g & 1023;

    f32x4 acc[4][4] = {};
    gemm_core128(xb, Wcat, m0, n0g, t, AsF, BsF, acc);

    const int w = t >> 6, lane = t & 63, l15 = lane & 15, quad = lane >> 4;
    const int wm = (w & 1) * 64, wn = (w >> 1) * 64;
    const float* bias = (which == 0) ? bq : (which == 1) ? bk : bv;
    float br[4];
    #pragma unroll
    for (int ns = 0; ns < 4; ++ns) br[ns] = bias[n_in + wn + ns*16 + l15];

    if (which == 2) {
        #pragma unroll
        for (int ms = 0; ms < 4; ++ms)
            #pragma unroll
            for (int ns = 0; ns < 4; ++ns) {
                h16x4 pk;
                #pragma unroll
                for (int rg = 0; rg < 4; ++rg) pk[rg] = (_Float16)(acc[ms][ns][rg] + br[ns]);
                *reinterpret_cast<h16x4*>(
                    &Vth[(size_t)(n_in + wn + ns*16 + l15) * SEQ + m0 + wm + ms*16 + quad*4]) = pk;
            }
    } else {
        const float s = (which == 0) ? 0.1803368787f : 1.0f;  // 0.125 * log2(e)
        _Float16* C = (which == 0) ? Qh : Kh;
        __syncthreads();   // all waves done with staging LDS
        _Float16* tile = (_Float16*)SM + w * 64 * LDP;   // per-wave 64x72 region
        #pragma unroll
        for (int ms = 0; ms < 4; ++ms)
            #pragma unroll
            for (int ns = 0; ns < 4; ++ns)
                #pragma unroll
                for (int rg = 0; rg < 4; ++rg)
                    tile[(ms*16 + quad*4 + rg) * LDP + ns*16 + l15] =
                        (_Float16)((acc[ms][ns][rg] + br[ns]) * s);
        asm volatile("s_waitcnt lgkmcnt(0)" ::: "memory");   // same-wave drain
        const int er = lane >> 3, ec = (lane & 7) * 8;
        #pragma unroll
        for (int p = 0; p < 8; ++p) {
            const h16x8 v = *reinterpret_cast<const h16x8*>(&tile[(er + p*8) * LDP + ec]);
            *reinterpret_cast<h16x8*>(
                &C[(size_t)(m0 + wm + er + p*8) * DMODEL + n_in + wn + ec]) = v;
        }
    }
}

// ---------------------------------------------------------------------------
// 128x64 GEMM core with DMA staging, for the output projection.
// ---------------------------------------------------------------------------
__device__ __forceinline__ void gemm_core64(const __bf16* __restrict__ A,
                                            const __bf16* __restrict__ W,
                                            int m0, int n0, int t,
                                            __bf16* AsF, __bf16* BsF,
                                            f32x4 acc[2][4])
{
    const int w = t >> 6, lane = t & 63, l15 = lane & 15, quad = lane >> 4;
    const int lr = lane >> 3, lc = lane & 7;
    for (int k0 = 0; k0 < DMODEL; k0 += 64) {
        __syncthreads();
        #pragma unroll
        for (int p = 0; p < 4; ++p) {
            const int n = w*4 + p;
            const int r = n*8 + lr;
            const int cl = lc ^ (r & 7);
            GLOAD_LDS16(&A[(size_t)(m0 + r) * DMODEL + k0 + cl*8], &AsF[n*512]);
        }
        #pragma unroll
        for (int p = 0; p < 2; ++p) {
            const int n = w*2 + p;
            const int r = n*8 + lr;
            const int cl = lc ^ (r & 7);
            GLOAD_LDS16(&W[(size_t)(n0 + r) * DMODEL + k0 + cl*8], &BsF[n*512]);
        }
        __syncthreads();
        #pragma unroll
        for (int kb = 0; kb < 2; ++kb) {
            const int phys = ((kb*4 + quad) ^ (l15 & 7)) * 8;
            bf16x8 af0 = *reinterpret_cast<const bf16x8*>(&AsF[(w*32 + l15)*64 + phys]);
            bf16x8 af1 = *reinterpret_cast<const bf16x8*>(&AsF[(w*32 + 16 + l15)*64 + phys]);
            #pragma unroll
            for (int ns = 0; ns < 4; ++ns) {
                const bf16x8 bfr = *reinterpret_cast<const bf16x8*>(&BsF[(ns*16 + l15)*64 + phys]);
                acc[0][ns] = __builtin_amdgcn_mfma_f32_16x16x32_bf16(af0, bfr, acc[0][ns], 0, 0, 0);
                acc[1][ns] = __builtin_amdgcn_mfma_f32_16x16x32_bf16(af1, bfr, acc[1][ns], 0, 0, 0);
            }
        }
    }
}

__global__ __launch_bounds__(256, 4)
void gemm_out(const __bf16* __restrict__ Ob, const __bf16* __restrict__ Wob,
              const float* __restrict__ bo, float* __restrict__ out)
{
    __shared__ __bf16 AsF[128*64];
    __shared__ __bf16 BsF[64*64];
    const int t = threadIdx.x;
    const int n0 = blockIdx.x * 64;
    const int m0 = blockIdx.y * 128;

    f32x4 acc[2][4] = {};
    gemm_core64(Ob, Wob, m0, n0, t, AsF, BsF, acc);

    const int lane = t & 63, l15 = lane & 15, quad = lane >> 4, w = t >> 6;
    float br[4];
    #pragma unroll
    for (int ns = 0; ns < 4; ++ns) br[ns] = bo[n0 + ns*16 + l15];
    #pragma unroll
    for (int ms = 0; ms < 2; ++ms)
        #pragma unroll
        for (int ns = 0; ns < 4; ++ns)
            #pragma unroll
            for (int rg = 0; rg < 4; ++rg)
                out[(size_t)(m0 + w*32 + ms*16 + quad*4 + rg) * DMODEL + n0 + ns*16 + l15] =
                    acc[ms][ns][rg] + br[ns];
}

// ---------------------------------------------------------------------------
// Causal flash attention, V13 = V6 + XCD-locality decode (T1). Flat grid of
// 768 blocks; block b -> xcd = b&7 (round-robin dispatch), j = b>>3 in [0,96):
// h = xcd*2 + (j>=48), u = j%48. All 96 blocks of heads {2x,2x+1} land on
// XCD x, whose 32 CUs hold exactly 96 resident blocks (3/CU) -> per-XCD
// working set = 2 heads x (Q+K+V = 1.5MB) = 3MB < 4MB L2. V6's layout spread
// ~5-6 heads per XCD (7.5MB > L2) -> thrash: FETCH 110MB vs 24MB ideal.
// Rest identical to verified V6 (equal 22-tile units, 2-buffer DMA LDS).
// ---------------------------------------------------------------------------
__global__ __launch_bounds__(256, 3)
void attn_mfma(const _Float16* __restrict__ Q, const _Float16* __restrict__ K,
               const _Float16* __restrict__ Vt, __bf16* __restrict__ O,
               _Float16* __restrict__ partA, _Float16* __restrict__ partB,
               float* __restrict__ lpart)
{
    __shared__ _Float16 KsF[2][64*64];   // [key][d], chunk-XOR swizzled (DMA)
    __shared__ _Float16 VsF[2][64*64];   // [d][key], chunk-XOR swizzled (DMA)

    const int t = threadIdx.x;
    const int w = t >> 6;
    const int lane = t & 63, l15 = lane & 15, quad = lane >> 4;
    const int lr = lane >> 3, lc = lane & 7;
    // XCD-locality decode: blocks of head h live on XCD h/2 only.
    const int b = blockIdx.x;
    const int xcd = b & 7;
    const int j = b >> 3;                // 0..95
    const int h = xcd*2 + (j >= 48 ? 1 : 0);
    const int u = (j >= 48) ? j - 48 : j;

    const int cl = lc ^ lr;
    const int rA = (w*2 + 0)*8 + lr, rB = (w*2 + 1)*8 + lr;
    const int dA = (w*2 + 0)*512,   dB = (w*2 + 1)*512;
    const h16x4 vone = {(_Float16)1.f, (_Float16)1.f, (_Float16)1.f, (_Float16)1.f};

    int g = u * 22;                      // global tile cursor
    const int gend = g + 22;
    int qt = 0;
    while ((qt + 1) * (qt + 2) <= g) ++qt;   // S(qt) <= g < S(qt+1)

    while (g < gend) {
        const int S = qt * (qt + 1);
        const int rowlen = 2*qt + 2;
        const int ts = g - S;
        const int rem = gend - S;
        const int te = (rowlen < rem) ? rowlen : rem;    // local tile range [ts,te)
        const int s0 = qt*128 + w*16;    // slice0 row base
        const int s1 = s0 + 64;          // slice1 row base

        // Q B-frags (x32: lane n=q=l15 holds d=quad*8+j), both slices.
        h16x8 bq8[2][2];
        #pragma unroll
        for (int kb = 0; kb < 2; ++kb) {
            bq8[0][kb] = *reinterpret_cast<const h16x8*>(
                &Q[(size_t)(s0 + l15) * DMODEL + h*DK + kb*32 + quad*8]);
            bq8[1][kb] = *reinterpret_cast<const h16x8*>(
                &Q[(size_t)(s1 + l15) * DMODEL + h*DK + kb*32 + quad*8]);
        }

        // staging sources for this segment (XOR-pre-swizzled; dest linear)
        const _Float16* kpA = &K [(size_t)(ts*64 + rA) * DMODEL + h*DK + cl*8];
        const _Float16* kpB = &K [(size_t)(ts*64 + rB) * DMODEL + h*DK + cl*8];
        const _Float16* vpA = &Vt[(size_t)(h*DK + rA) * SEQ + ts*64 + cl*8];
        const _Float16* vpB = &Vt[(size_t)(h*DK + rB) * SEQ + ts*64 + cl*8];

#define STAGE_KV(bi) do {                                     \
        GLOAD_LDS16(kpA, &KsF[bi][dA]);                       \
        GLOAD_LDS16(kpB, &KsF[bi][dB]);                       \
        GLOAD_LDS16(vpA, &VsF[bi][dA]);                       \
        GLOAD_LDS16(vpB, &VsF[bi][dB]);                       \
        kpA += (size_t)64*DMODEL; kpB += (size_t)64*DMODEL;   \
        vpA += 64; vpB += 64; } while (0)

        f32x4 acc[2][4] = {};        // [slice][dsub]; C: col=d=l15, row=q=quad*4+rg
        f32x4 accl[2] = {};          // denom rowsums via ones-MFMA

        STAGE_KV(0);                 // prologue: stage tile ts into buffer 0
        __syncthreads();             // drains prologue DMA + barrier

        int pbuf = 0;
        for (int tk = ts; tk < te; ++tk, pbuf ^= 1) {
            if (tk + 1 < te) STAGE_KV(pbuf ^ 1);   // issue next tile's DMA first

            const int j0 = tk * 64;
            const bool act0 = (j0 <= s0 + 15);   // slice0 still in causal range
            const bool msk0 = (j0 + 63 > s0);    // wave-uniform
            const bool msk1 = (j0 + 63 > s1);    // wave-uniform
            const int rel0 = s0 - j0 + l15;
            const int rel1 = s1 - j0 + l15;

            // ---- S^T = K . Q^T (x32); K A-frags shared by both slices ----
            h16x4 ap[2][4];
            #pragma unroll
            for (int st = 0; st < 4; ++st) {
                const h16x8 ak0 = *reinterpret_cast<const h16x8*>(
                    &KsF[pbuf][(st*16 + l15)*64 + ((quad ^ (l15 & 7)))*8]);
                const h16x8 ak1 = *reinterpret_cast<const h16x8*>(
                    &KsF[pbuf][(st*16 + l15)*64 + (((4 + quad) ^ (l15 & 7)))*8]);
                // slice 1 (always active)
                {
                    f32x4 cc = {0.f, 0.f, 0.f, 0.f};
                    cc = __builtin_amdgcn_mfma_f32_16x16x32_f16(ak0, bq8[1][0], cc, 0, 0, 0);
                    cc = __builtin_amdgcn_mfma_f32_16x16x32_f16(ak1, bq8[1][1], cc, 0, 0, 0);
                    float pv[4];
                    if (msk1) {
                        #pragma unroll
                        for (int rg = 0; rg < 4; ++rg) {
                            const float e = EXP2R(cc[rg]);
                            pv[rg] = (st*16 + quad*4 + rg > rel1) ? 0.f : e;
                        }
                    } else {
                        #pragma unroll
                        for (int rg = 0; rg < 4; ++rg) pv[rg] = EXP2R(cc[rg]);
                    }
                    const h16x2 lo = cvt_pk_h16(pv[0], pv[1]);
                    const h16x2 hi = cvt_pk_h16(pv[2], pv[3]);
                    ap[1][st] = (h16x4){lo[0], lo[1], hi[0], hi[1]};
                    accl[1] = __builtin_amdgcn_mfma_f32_16x16x16f16(ap[1][st], vone, accl[1], 0, 0, 0);
                }
                // slice 0
                if (act0) {
                    f32x4 cc = {0.f, 0.f, 0.f, 0.f};
                    cc = __builtin_amdgcn_mfma_f32_16x16x32_f16(ak0, bq8[0][0], cc, 0, 0, 0);
                    cc = __builtin_amdgcn_mfma_f32_16x16x32_f16(ak1, bq8[0][1], cc, 0, 0, 0);
                    float pv[4];
                    if (msk0) {
                        #pragma unroll
                        for (int rg = 0; rg < 4; ++rg) {
                            const float e = EXP2R(cc[rg]);
                            pv[rg] = (st*16 + quad*4 + rg > rel0) ? 0.f : e;
                        }
                    } else {
                        #pragma unroll
                        for (int rg = 0; rg < 4; ++rg) pv[rg] = EXP2R(cc[rg]);
                    }
                    const h16x2 lo = cvt_pk_h16(pv[0], pv[1]);
                    const h16x2 hi = cvt_pk_h16(pv[2], pv[3]);
                    ap[0][st] = (h16x4){lo[0], lo[1], hi[0], hi[1]};
                    accl[0] = __builtin_amdgcn_mfma_f32_16x16x16f16(ap[0][st], vone, accl[0], 0, 0, 0);
                }
            }

            // ---- O^ += P . V (x16); V B-frags shared by both slices ----
            #pragma unroll
            for (int ds_ = 0; ds_ < 4; ++ds_) {
                #pragma unroll
                for (int st = 0; st < 4; ++st) {
                    const h16x4 bv = *reinterpret_cast<const h16x4*>(
                        &VsF[pbuf][(ds_*16 + l15)*64 +
                                   (((st*2 + (quad >> 1)) ^ (l15 & 7)))*8 + (quad & 1)*4]);
                    acc[1][ds_] = __builtin_amdgcn_mfma_f32_16x16x16f16(ap[1][st], bv, acc[1][ds_], 0, 0, 0);
                    if (act0)
                        acc[0][ds_] = __builtin_amdgcn_mfma_f32_16x16x16f16(ap[0][st], bv, acc[0][ds_], 0, 0, 0);
                }
            }
            __syncthreads();   // readers of pbuf done + next-tile DMA drained
        }
#undef STAGE_KV

        // ---- segment epilogue ----
        if (ts == 0 && te == rowlen) {
            // full row in this chunk: normalize and write bf16 O
            #pragma unroll
            for (int s = 0; s < 2; ++s) {
                const int base = s ? s1 : s0;
                #pragma unroll
                for (int rg = 0; rg < 4; ++rg) {
                    const float inv = 1.0f / accl[s][rg];
                    const size_t row = (size_t)(base + quad*4 + rg) * DMODEL + h * DK;
                    #pragma unroll
                    for (int ds_ = 0; ds_ < 4; ++ds_)
                        O[row + ds_*16 + l15] = (__bf16)(acc[s][ds_][rg] * inv);
                }
            }
        } else {
            const int side = (g == u*22) ? 0 : 1;   // first segment of chunk?
            const int slot = (h*48 + u)*2 + side;
            _Float16* p = (slot < 1024) ? partA + (size_t)slot * 8192
                                        : partB + (size_t)(slot - 1024) * 8192;
            #pragma unroll
            for (int s = 0; s < 2; ++s) {
                #pragma unroll
                for (int rg = 0; rg < 4; ++rg) {
                    const int lrow = s*64 + w*16 + quad*4 + rg;
                    #pragma unroll
                    for (int ds_ = 0; ds_ < 4; ++ds_)
                        p[lrow*64 + ds_*16 + l15] = (_Float16)acc[s][ds_][rg];
                    if (l15 == 0) lpart[(size_t)slot*128 + lrow] = accl[s][rg];
                }
            }
        }
        g = S + te;
        ++qt;
    }
}

// ---------------------------------------------------------------------------
// Combine fp16 partials for rows split across chunks: O = sum p / sum l.
// Row qt spans chunks c0..c1; side(c) = (22c >= S(qt)) ? 0 : 1.
// ---------------------------------------------------------------------------
__global__ __launch_bounds__(256)
void attn_combine(const _Float16* __restrict__ partA, const _Float16* __restrict__ partB,
                  const float* __restrict__ lpart, __bf16* __restrict__ O)
{
    const int t = threadIdx.x;
    const int qt = blockIdx.x;           // 0..31
    const int h  = blockIdx.y;
    const int S = qt*(qt+1);
    const int rowlen = 2*qt + 2;
    const int c0 = S / 22;
    const int c1 = (S + rowlen - 1) / 22;
    if (c0 == c1) return;                // finalized in attn_mfma
    const int r  = t >> 1;               // 0..127 local row
    const int d0 = (t & 1) * 32;

    float a[4][8] = {};
    float l = 0.f;
    for (int c = c0; c <= c1; ++c) {
        const int side = (22*c >= S) ? 0 : 1;
        const int sl = (h*48 + c)*2 + side;
        const _Float16* pc = (sl < 1024) ? partA + (size_t)sl * 8192
                                         : partB + (size_t)(sl - 1024) * 8192;
        l += lpart[(size_t)sl*128 + r];
        #pragma unroll
        for (int i = 0; i < 4; ++i) {
            const h16x8 v = *reinterpret_cast<const h16x8*>(&pc[r*64 + d0 + i*8]);
            #pragma unroll
            for (int j = 0; j < 8; ++j) a[i][j] += (float)v[j];
        }
    }
    const float inv = 1.0f / l;
    const size_t grow = (size_t)(qt*128 + r) * DMODEL + h*64 + d0;
    #pragma unroll
    for (int i = 0; i < 4; ++i) {
        bf16x8 pk;
        #pragma unroll
        for (int j = 0; j < 8; ++j) pk[j] = (__bf16)(a[i][j] * inv);
        *reinterpret_cast<bf16x8*>(&O[grow + i*8]) = pk;
    }
}

// ---------------------------------------------------------------------------
extern "C" void kernel_launch(void* const* d_in, const int* in_sizes, int n_in,
                              void* d_out, int out_size, void* d_ws, size_t ws_size,
                              hipStream_t stream) {
    const float* x  = (const float*)d_in[0];
    const float* Wq = (const float*)d_in[1];
    const float* bq = (const float*)d_in[2];
    const float* Wk = (const float*)d_in[3];
    const float* bk = (const float*)d_in[4];
    const float* Wv = (const float*)d_in[5];
    const float* bv = (const float*)d_in[6];
    const float* Wo = (const float*)d_in[7];
    const float* bo = (const float*)d_in[8];
    float* out = (float*)d_out;

    const size_t M1 = 1u << 20;
    __bf16* base = (__bf16*)d_ws;
    __bf16*    xb   = base;                          // 4M bf16 (free after gemm_qkv)
    __bf16*    Wcat = base + 4*M1;                   // Wq|Wk|Wv (free after gemm_qkv)
    __bf16*    Wob  = base + 7*M1;                   // 1M bf16
    _Float16*  Qh   = (_Float16*)(base + 8*M1);      // 4M fp16 each
    _Float16*  Kh   = (_Float16*)(base + 12*M1);
    _Float16*  Vth  = (_Float16*)(base + 16*M1);
    __bf16*    Ob   = base + 20*M1;                  // 4M bf16
    // fp16 partials: slots 0..1023 in d_out (16 MB), 1024..1535 in xb (8 MB)
    _Float16*  partA = (_Float16*)out;
    _Float16*  partB = (_Float16*)xb;
    // per-slot row sums: 1536*128 fp32 = 786 KB in the Wcat region
    float*     lpart = (float*)Wcat;

    cvt_all<<<4096, 256, 0, stream>>>(x, Wq, Wk, Wv, Wo, base);
    gemm_qkv<<<dim3(24, 32), 256, 0, stream>>>(xb, Wcat, bq, bk, bv, Qh, Kh, Vth);
    attn_mfma<<<768, 256, 0, stream>>>(Qh, Kh, Vth, Ob, partA, partB, lpart);
    attn_combine<<<dim3(32, NH), 256, 0, stream>>>(partA, partB, lpart, Ob);
    gemm_out<<<dim3(16, 32), 256, 0, stream>>>(Ob, Wob, bo, out);
}

// Round 15
// 198.071 us; speedup vs baseline: 1.1474x; 1.0416x over previous
//
#include <hip/hip_runtime.h>
#include <math.h>

#define SEQ 4096
#define DMODEL 1024
#define NH 16
#define DK 64
#define LDP 72   // padded LDS row (16-bit elems): conflict-free b64/b128 frag reads

typedef __bf16    bf16x8 __attribute__((ext_vector_type(8)));
typedef float     f32x4  __attribute__((ext_vector_type(4)));
typedef __fp16    fp16x2 __attribute__((ext_vector_type(2)));
typedef _Float16  h16x2  __attribute__((ext_vector_type(2)));
typedef _Float16  h16x4  __attribute__((ext_vector_type(4)));
typedef _Float16  h16x8  __attribute__((ext_vector_type(8)));

// global->LDS DMA, 16 B per lane; LDS dest = uniform base + lane*16 (no pad!)
#define GLOAD_LDS16(g, l) __builtin_amdgcn_global_load_lds(                     \
    (const __attribute__((address_space(1))) unsigned int*)(g),                 \
    (__attribute__((address_space(3))) unsigned int*)(l), 16, 0, 0)

// packed f32->f16 (RTZ), re-typed to _Float16x2
__device__ __forceinline__ h16x2 cvt_pk_h16(float a, float b) {
    fp16x2 r = __builtin_amdgcn_cvt_pkrtz(a, b);
    return __builtin_bit_cast(h16x2, r);
}

// raw v_exp_f32 (no denormal-guard expansion; inputs bounded)
#define EXP2R(x) __builtin_amdgcn_exp2f(x)

// ---------------------------------------------------------------------------
// Convert x (4M) + Wq/Wk/Wv/Wo (1M each) fp32 -> bf16 into contiguous ws.
// ---------------------------------------------------------------------------
__global__ __launch_bounds__(256)
void cvt_all(const float* __restrict__ x, const float* __restrict__ Wq,
             const float* __restrict__ Wk, const float* __restrict__ Wv,
             const float* __restrict__ Wo, __bf16* __restrict__ dst)
{
    const size_t M1 = 1u << 20;
    const size_t e = ((size_t)blockIdx.x * 256 + threadIdx.x) * 8;
    const float* src; size_t off;
    if      (e < 4*M1) { src = x;  off = e;        }
    else if (e < 5*M1) { src = Wq; off = e - 4*M1; }
    else if (e < 6*M1) { src = Wk; off = e - 5*M1; }
    else if (e < 7*M1) { src = Wv; off = e - 6*M1; }
    else               { src = Wo; off = e - 7*M1; }
    const float4 f0 = *reinterpret_cast<const float4*>(&src[off]);
    const float4 f1 = *reinterpret_cast<const float4*>(&src[off + 4]);
    bf16x8 pk;
    pk[0]=(__bf16)f0.x; pk[1]=(__bf16)f0.y; pk[2]=(__bf16)f0.z; pk[3]=(__bf16)f0.w;
    pk[4]=(__bf16)f1.x; pk[5]=(__bf16)f1.y; pk[6]=(__bf16)f1.z; pk[7]=(__bf16)f1.w;
    *reinterpret_cast<bf16x8*>(&dst[e]) = pk;
}

// ---------------------------------------------------------------------------
// 128x128 GEMM core with global_load_lds staging (XOR chunk swizzle).
// ---------------------------------------------------------------------------
__device__ __forceinline__ void gemm_core128(const __bf16* __restrict__ A,
                                             const __bf16* __restrict__ W,
                                             int m0, int n0, int t,
                                             __bf16* AsF, __bf16* BsF,
                                             f32x4 acc[4][4])
{
    const int w = t >> 6, lane = t & 63, l15 = lane & 15, quad = lane >> 4;
    const int wm = (w & 1) * 64, wn = (w >> 1) * 64;
    const int lr = lane >> 3, lc = lane & 7;
    for (int k0 = 0; k0 < DMODEL; k0 += 64) {
        __syncthreads();
        #pragma unroll
        for (int p = 0; p < 4; ++p) {
            const int n = w*4 + p;
            const int r = n*8 + lr;
            const int cl = lc ^ (r & 7);
            GLOAD_LDS16(&A[(size_t)(m0 + r) * DMODEL + k0 + cl*8], &AsF[n*512]);
            GLOAD_LDS16(&W[(size_t)(n0 + r) * DMODEL + k0 + cl*8], &BsF[n*512]);
        }
        __syncthreads();
        #pragma unroll
        for (int kb = 0; kb < 2; ++kb) {
            const int phys = ((kb*4 + quad) ^ (l15 & 7)) * 8;
            bf16x8 af[4], bfr[4];
            #pragma unroll
            for (int i = 0; i < 4; ++i) {
                af[i]  = *reinterpret_cast<const bf16x8*>(&AsF[(wm + i*16 + l15)*64 + phys]);
                bfr[i] = *reinterpret_cast<const bf16x8*>(&BsF[(wn + i*16 + l15)*64 + phys]);
            }
            #pragma unroll
            for (int ms = 0; ms < 4; ++ms)
                #pragma unroll
                for (int ns = 0; ns < 4; ++ns)
                    acc[ms][ns] = __builtin_amdgcn_mfma_f32_16x16x32_bf16(af[ms], bfr[ns], acc[ms][ns], 0, 0, 0);
        }
    }
}

// ---------------------------------------------------------------------------
// Fused QKV projection -> fp16. [0,1024)=Q scaled 0.125*log2e; [1024,2048)=K;
// [2048,3072)=V transposed Vt[d][s]. Q/K epilogue via per-wave LDS transpose.
// ---------------------------------------------------------------------------
__global__ __launch_bounds__(256, 3)
void gemm_qkv(const __bf16* __restrict__ xb, const __bf16* __restrict__ Wcat,
              const float* __restrict__ bq, const float* __restrict__ bk,
              const float* __restrict__ bv,
              _Float16* __restrict__ Qh, _Float16* __restrict__ Kh, _Float16* __restrict__ Vth)
{
    __shared__ __bf16 SM[4*64*LDP];      // staging uses first 32 KB
    __bf16* AsF = SM;
    __bf16* BsF = SM + 8192;
    const int t = threadIdx.x;
    const int n0g = blockIdx.x * 128;
    const int m0  = blockIdx.y * 128;
    const int which = n0g >> 10;
    const int n_in  = n0g & 1023;

    f32x4 acc[4][4] = {};
    gemm_core128(xb, Wcat, m0, n0g, t, AsF, BsF, acc);

    const int w = t >> 6, lane = t & 63, l15 = lane & 15, quad = lane >> 4;
    const int wm = (w & 1) * 64, wn = (w >> 1) * 64;
    const float* bias = (which == 0) ? bq : (which == 1) ? bk : bv;
    float br[4];
    #pragma unroll
    for (int ns = 0; ns < 4; ++ns) br[ns] = bias[n_in + wn + ns*16 + l15];

    if (which == 2) {
        #pragma unroll
        for (int ms = 0; ms < 4; ++ms)
            #pragma unroll
            for (int ns = 0; ns < 4; ++ns) {
                h16x4 pk;
                #pragma unroll
                for (int rg = 0; rg < 4; ++rg) pk[rg] = (_Float16)(acc[ms][ns][rg] + br[ns]);
                *reinterpret_cast<h16x4*>(
                    &Vth[(size_t)(n_in + wn + ns*16 + l15) * SEQ + m0 + wm + ms*16 + quad*4]) = pk;
            }
    } else {
        const float s = (which == 0) ? 0.1803368787f : 1.0f;  // 0.125 * log2(e)
        _Float16* C = (which == 0) ? Qh : Kh;
        __syncthreads();   // all waves done with staging LDS
        _Float16* tile = (_Float16*)SM + w * 64 * LDP;   // per-wave 64x72 region
        #pragma unroll
        for (int ms = 0; ms < 4; ++ms)
            #pragma unroll
            for (int ns = 0; ns < 4; ++ns)
                #pragma unroll
                for (int rg = 0; rg < 4; ++rg)
                    tile[(ms*16 + quad*4 + rg) * LDP + ns*16 + l15] =
                        (_Float16)((acc[ms][ns][rg] + br[ns]) * s);
        asm volatile("s_waitcnt lgkmcnt(0)" ::: "memory");   // same-wave drain
        const int er = lane >> 3, ec = (lane & 7) * 8;
        #pragma unroll
        for (int p = 0; p < 8; ++p) {
            const h16x8 v = *reinterpret_cast<const h16x8*>(&tile[(er + p*8) * LDP + ec]);
            *reinterpret_cast<h16x8*>(
                &C[(size_t)(m0 + wm + er + p*8) * DMODEL + n_in + wn + ec]) = v;
        }
    }
}

// ---------------------------------------------------------------------------
// Output projection, V15: 64x64 tiles (isolated re-test of V12's gemm_out —
// V12 changed BOTH GEMMs and regressed; the traffic arithmetic says the
// damage was gemm_qkv's A-re-reads, while this kernel's 2x waves/CU
// (8 -> 16; 1024 blocks = 4/CU uniform, LDS 16KB) attacks the pipeline's
// lowest-TLP kernel. B re-reads +64MB but Wob is 2MB L2-resident.
// ---------------------------------------------------------------------------
__global__ __launch_bounds__(256, 4)
void gemm_out(const __bf16* __restrict__ Ob, const __bf16* __restrict__ Wob,
              const float* __restrict__ bo, float* __restrict__ out)
{
    __shared__ __bf16 AsF[64*64];
    __shared__ __bf16 BsF[64*64];
    const int t = threadIdx.x;
    const int n0 = blockIdx.x * 64;
    const int m0 = blockIdx.y * 64;
    const int w = t >> 6, lane = t & 63, l15 = lane & 15, quad = lane >> 4;
    const int lr = lane >> 3, lc = lane & 7;

    f32x4 acc[4] = {};                   // wave rows w*16..w*16+15, 64 cols
    for (int k0 = 0; k0 < DMODEL; k0 += 64) {
        __syncthreads();
        #pragma unroll
        for (int p = 0; p < 2; ++p) {
            const int n = w*2 + p;
            const int r = n*8 + lr;
            const int cl = lc ^ (r & 7);
            GLOAD_LDS16(&Ob [(size_t)(m0 + r) * DMODEL + k0 + cl*8], &AsF[n*512]);
            GLOAD_LDS16(&Wob[(size_t)(n0 + r) * DMODEL + k0 + cl*8], &BsF[n*512]);
        }
        __syncthreads();
        #pragma unroll
        for (int kb = 0; kb < 2; ++kb) {
            const int phys = ((kb*4 + quad) ^ (l15 & 7)) * 8;
            const bf16x8 af = *reinterpret_cast<const bf16x8*>(&AsF[(w*16 + l15)*64 + phys]);
            #pragma unroll
            for (int ns = 0; ns < 4; ++ns) {
                const bf16x8 bfr = *reinterpret_cast<const bf16x8*>(&BsF[(ns*16 + l15)*64 + phys]);
                acc[ns] = __builtin_amdgcn_mfma_f32_16x16x32_bf16(af, bfr, acc[ns], 0, 0, 0);
            }
        }
    }

    float br[4];
    #pragma unroll
    for (int ns = 0; ns < 4; ++ns) br[ns] = bo[n0 + ns*16 + l15];
    #pragma unroll
    for (int ns = 0; ns < 4; ++ns)
        #pragma unroll
        for (int rg = 0; rg < 4; ++rg)
            out[(size_t)(m0 + w*16 + quad*4 + rg) * DMODEL + n0 + ns*16 + l15] =
                acc[ns][rg] + br[ns];
}

// ---------------------------------------------------------------------------
// Causal flash attention, V13 (kept — counter-verified best): V6 structure +
// XCD-locality decode. Flat grid 768; b -> xcd = b&7, j = b>>3, h = xcd*2 +
// (j>=48), u = j%48: heads {2x,2x+1} pinned to XCD x -> per-XCD working set
// 3MB < 4MB L2. Measured: FETCH 110 -> 12.7 MB (ideal), attn 68 -> 65.5us.
// ---------------------------------------------------------------------------
__global__ __launch_bounds__(256, 3)
void attn_mfma(const _Float16* __restrict__ Q, const _Float16* __restrict__ K,
               const _Float16* __restrict__ Vt, __bf16* __restrict__ O,
               _Float16* __restrict__ partA, _Float16* __restrict__ partB,
               float* __restrict__ lpart)
{
    __shared__ _Float16 KsF[2][64*64];   // [key][d], chunk-XOR swizzled (DMA)
    __shared__ _Float16 VsF[2][64*64];   // [d][key], chunk-XOR swizzled (DMA)

    const int t = threadIdx.x;
    const int w = t >> 6;
    const int lane = t & 63, l15 = lane & 15, quad = lane >> 4;
    const int lr = lane >> 3, lc = lane & 7;
    // XCD-locality decode: blocks of head h live on XCD h/2 only.
    const int b = blockIdx.x;
    const int xcd = b & 7;
    const int j = b >> 3;                // 0..95
    const int h = xcd*2 + (j >= 48 ? 1 : 0);
    const int u = (j >= 48) ? j - 48 : j;

    const int cl = lc ^ lr;
    const int rA = (w*2 + 0)*8 + lr, rB = (w*2 + 1)*8 + lr;
    const int dA = (w*2 + 0)*512,   dB = (w*2 + 1)*512;
    const h16x4 vone = {(_Float16)1.f, (_Float16)1.f, (_Float16)1.f, (_Float16)1.f};

    int g = u * 22;                      // global tile cursor
    const int gend = g + 22;
    int qt = 0;
    while ((qt + 1) * (qt + 2) <= g) ++qt;   // S(qt) <= g < S(qt+1)

    while (g < gend) {
        const int S = qt * (qt + 1);
        const int rowlen = 2*qt + 2;
        const int ts = g - S;
        const int rem = gend - S;
        const int te = (rowlen < rem) ? rowlen : rem;    // local tile range [ts,te)
        const int s0 = qt*128 + w*16;    // slice0 row base
        const int s1 = s0 + 64;          // slice1 row base

        // Q B-frags (x32: lane n=q=l15 holds d=quad*8+j), both slices.
        h16x8 bq8[2][2];
        #pragma unroll
        for (int kb = 0; kb < 2; ++kb) {
            bq8[0][kb] = *reinterpret_cast<const h16x8*>(
                &Q[(size_t)(s0 + l15) * DMODEL + h*DK + kb*32 + quad*8]);
            bq8[1][kb] = *reinterpret_cast<const h16x8*>(
                &Q[(size_t)(s1 + l15) * DMODEL + h*DK + kb*32 + quad*8]);
        }

        // staging sources for this segment (XOR-pre-swizzled; dest linear)
        const _Float16* kpA = &K [(size_t)(ts*64 + rA) * DMODEL + h*DK + cl*8];
        const _Float16* kpB = &K [(size_t)(ts*64 + rB) * DMODEL + h*DK + cl*8];
        const _Float16* vpA = &Vt[(size_t)(h*DK + rA) * SEQ + ts*64 + cl*8];
        const _Float16* vpB = &Vt[(size_t)(h*DK + rB) * SEQ + ts*64 + cl*8];

#define STAGE_KV(bi) do {                                     \
        GLOAD_LDS16(kpA, &KsF[bi][dA]);                       \
        GLOAD_LDS16(kpB, &KsF[bi][dB]);                       \
        GLOAD_LDS16(vpA, &VsF[bi][dA]);                       \
        GLOAD_LDS16(vpB, &VsF[bi][dB]);                       \
        kpA += (size_t)64*DMODEL; kpB += (size_t)64*DMODEL;   \
        vpA += 64; vpB += 64; } while (0)

        f32x4 acc[2][4] = {};        // [slice][dsub]; C: col=d=l15, row=q=quad*4+rg
        f32x4 accl[2] = {};          // denom rowsums via ones-MFMA

        STAGE_KV(0);                 // prologue: stage tile ts into buffer 0
        __syncthreads();             // drains prologue DMA + barrier

        int pbuf = 0;
        for (int tk = ts; tk < te; ++tk, pbuf ^= 1) {
            if (tk + 1 < te) STAGE_KV(pbuf ^ 1);   // issue next tile's DMA first

            const int j0 = tk * 64;
            const bool act0 = (j0 <= s0 + 15);   // slice0 still in causal range
            const bool msk0 = (j0 + 63 > s0);    // wave-uniform
            const bool msk1 = (j0 + 63 > s1);    // wave-uniform
            const int rel0 = s0 - j0 + l15;
            const int rel1 = s1 - j0 + l15;

            // ---- S^T = K . Q^T (x32); K A-frags shared by both slices ----
            h16x4 ap[2][4];
            #pragma unroll
            for (int st = 0; st < 4; ++st) {
                const h16x8 ak0 = *reinterpret_cast<const h16x8*>(
                    &KsF[pbuf][(st*16 + l15)*64 + ((quad ^ (l15 & 7)))*8]);
                const h16x8 ak1 = *reinterpret_cast<const h16x8*>(
                    &KsF[pbuf][(st*16 + l15)*64 + (((4 + quad) ^ (l15 & 7)))*8]);
                // slice 1 (always active)
                {
                    f32x4 cc = {0.f, 0.f, 0.f, 0.f};
                    cc = __builtin_amdgcn_mfma_f32_16x16x32_f16(ak0, bq8[1][0], cc, 0, 0, 0);
                    cc = __builtin_amdgcn_mfma_f32_16x16x32_f16(ak1, bq8[1][1], cc, 0, 0, 0);
                    float pv[4];
                    if (msk1) {
                        #pragma unroll
                        for (int rg = 0; rg < 4; ++rg) {
                            const float e = EXP2R(cc[rg]);
                            pv[rg] = (st*16 + quad*4 + rg > rel1) ? 0.f : e;
                        }
                    } else {
                        #pragma unroll
                        for (int rg = 0; rg < 4; ++rg) pv[rg] = EXP2R(cc[rg]);
                    }
                    const h16x2 lo = cvt_pk_h16(pv[0], pv[1]);
                    const h16x2 hi = cvt_pk_h16(pv[2], pv[3]);
                    ap[1][st] = (h16x4){lo[0], lo[1], hi[0], hi[1]};
                    accl[1] = __builtin_amdgcn_mfma_f32_16x16x16f16(ap[1][st], vone, accl[1], 0, 0, 0);
                }
                // slice 0
                if (act0) {
                    f32x4 cc = {0.f, 0.f, 0.f, 0.f};
                    cc = __builtin_amdgcn_mfma_f32_16x16x32_f16(ak0, bq8[0][0], cc, 0, 0, 0);
                    cc = __builtin_amdgcn_mfma_f32_16x16x32_f16(ak1, bq8[0][1], cc, 0, 0, 0);
                    float pv[4];
                    if (msk0) {
                        #pragma unroll
                        for (int rg = 0; rg < 4; ++rg) {
                            const float e = EXP2R(cc[rg]);
                            pv[rg] = (st*16 + quad*4 + rg > rel0) ? 0.f : e;
                        }
                    } else {
                        #pragma unroll
                        for (int rg = 0; rg < 4; ++rg) pv[rg] = EXP2R(cc[rg]);
                    }
                    const h16x2 lo = cvt_pk_h16(pv[0], pv[1]);
                    const h16x2 hi = cvt_pk_h16(pv[2], pv[3]);
                    ap[0][st] = (h16x4){lo[0], lo[1], hi[0], hi[1]};
                    accl[0] = __builtin_amdgcn_mfma_f32_16x16x16f16(ap[0][st], vone, accl[0], 0, 0, 0);
                }
            }

            // ---- O^ += P . V (x16); V B-frags shared by both slices ----
            #pragma unroll
            for (int ds_ = 0; ds_ < 4; ++ds_) {
                #pragma unroll
                for (int st = 0; st < 4; ++st) {
                    const h16x4 bv = *reinterpret_cast<const h16x4*>(
                        &VsF[pbuf][(ds_*16 + l15)*64 +
                                   (((st*2 + (quad >> 1)) ^ (l15 & 7)))*8 + (quad & 1)*4]);
                    acc[1][ds_] = __builtin_amdgcn_mfma_f32_16x16x16f16(ap[1][st], bv, acc[1][ds_], 0, 0, 0);
                    if (act0)
                        acc[0][ds_] = __builtin_amdgcn_mfma_f32_16x16x16f16(ap[0][st], bv, acc[0][ds_], 0, 0, 0);
                }
            }
            __syncthreads();   // readers of pbuf done + next-tile DMA drained
        }
#undef STAGE_KV

        // ---- segment epilogue ----
        if (ts == 0 && te == rowlen) {
            // full row in this chunk: normalize and write bf16 O
            #pragma unroll
            for (int s = 0; s < 2; ++s) {
                const int base = s ? s1 : s0;
                #pragma unroll
                for (int rg = 0; rg < 4; ++rg) {
                    const float inv = 1.0f / accl[s][rg];
                    const size_t row = (size_t)(base + quad*4 + rg) * DMODEL + h * DK;
                    #pragma unroll
                    for (int ds_ = 0; ds_ < 4; ++ds_)
                        O[row + ds_*16 + l15] = (__bf16)(acc[s][ds_][rg] * inv);
                }
            }
        } else {
            const int side = (g == u*22) ? 0 : 1;   // first segment of chunk?
            const int slot = (h*48 + u)*2 + side;
            _Float16* p = (slot < 1024) ? partA + (size_t)slot * 8192
                                        : partB + (size_t)(slot - 1024) * 8192;
            #pragma unroll
            for (int s = 0; s < 2; ++s) {
                #pragma unroll
                for (int rg = 0; rg < 4; ++rg) {
                    const int lrow = s*64 + w*16 + quad*4 + rg;
                    #pragma unroll
                    for (int ds_ = 0; ds_ < 4; ++ds_)
                        p[lrow*64 + ds_*16 + l15] = (_Float16)acc[s][ds_][rg];
                    if (l15 == 0) lpart[(size_t)slot*128 + lrow] = accl[s][rg];
                }
            }
        }
        g = S + te;
        ++qt;
    }
}

// ---------------------------------------------------------------------------
// Combine fp16 partials for rows split across chunks: O = sum p / sum l.
// Row qt spans chunks c0..c1; side(c) = (22c >= S(qt)) ? 0 : 1.
// ---------------------------------------------------------------------------
__global__ __launch_bounds__(256)
void attn_combine(const _Float16* __restrict__ partA, const _Float16* __restrict__ partB,
                  const float* __restrict__ lpart, __bf16* __restrict__ O)
{
    const int t = threadIdx.x;
    const int qt = blockIdx.x;           // 0..31
    const int h  = blockIdx.y;
    const int S = qt*(qt+1);
    const int rowlen = 2*qt + 2;
    const int c0 = S / 22;
    const int c1 = (S + rowlen - 1) / 22;
    if (c0 == c1) return;                // finalized in attn_mfma
    const int r  = t >> 1;               // 0..127 local row
    const int d0 = (t & 1) * 32;

    float a[4][8] = {};
    float l = 0.f;
    for (int c = c0; c <= c1; ++c) {
        const int side = (22*c >= S) ? 0 : 1;
        const int sl = (h*48 + c)*2 + side;
        const _Float16* pc = (sl < 1024) ? partA + (size_t)sl * 8192
                                         : partB + (size_t)(sl - 1024) * 8192;
        l += lpart[(size_t)sl*128 + r];
        #pragma unroll
        for (int i = 0; i < 4; ++i) {
            const h16x8 v = *reinterpret_cast<const h16x8*>(&pc[r*64 + d0 + i*8]);
            #pragma unroll
            for (int j = 0; j < 8; ++j) a[i][j] += (float)v[j];
        }
    }
    const float inv = 1.0f / l;
    const size_t grow = (size_t)(qt*128 + r) * DMODEL + h*64 + d0;
    #pragma unroll
    for (int i = 0; i < 4; ++i) {
        bf16x8 pk;
        #pragma unroll
        for (int j = 0; j < 8; ++j) pk[j] = (__bf16)(a[i][j] * inv);
        *reinterpret_cast<bf16x8*>(&O[grow + i*8]) = pk;
    }
}

// ---------------------------------------------------------------------------
extern "C" void kernel_launch(void* const* d_in, const int* in_sizes, int n_in,
                              void* d_out, int out_size, void* d_ws, size_t ws_size,
                              hipStream_t stream) {
    const float* x  = (const float*)d_in[0];
    const float* Wq = (const float*)d_in[1];
    const float* bq = (const float*)d_in[2];
    const float* Wk = (const float*)d_in[3];
    const float* bk = (const float*)d_in[4];
    const float* Wv = (const float*)d_in[5];
    const float* bv = (const float*)d_in[6];
    const float* Wo = (const float*)d_in[7];
    const float* bo = (const float*)d_in[8];
    float* out = (float*)d_out;

    const size_t M1 = 1u << 20;
    __bf16* base = (__bf16*)d_ws;
    __bf16*    xb   = base;                          // 4M bf16 (free after gemm_qkv)
    __bf16*    Wcat = base + 4*M1;                   // Wq|Wk|Wv (free after gemm_qkv)
    __bf16*    Wob  = base + 7*M1;                   // 1M bf16
    _Float16*  Qh   = (_Float16*)(base + 8*M1);      // 4M fp16 each
    _Float16*  Kh   = (_Float16*)(base + 12*M1);
    _Float16*  Vth  = (_Float16*)(base + 16*M1);
    __bf16*    Ob   = base + 20*M1;                  // 4M bf16
    // fp16 partials: slots 0..1023 in d_out (16 MB), 1024..1535 in xb (8 MB)
    _Float16*  partA = (_Float16*)out;
    _Float16*  partB = (_Float16*)xb;
    // per-slot row sums: 1536*128 fp32 = 786 KB in the Wcat region
    float*     lpart = (float*)Wcat;

    cvt_all<<<4096, 256, 0, stream>>>(x, Wq, Wk, Wv, Wo, base);
    gemm_qkv<<<dim3(24, 32), 256, 0, stream>>>(xb, Wcat, bq, bk, bv, Qh, Kh, Vth);
    attn_mfma<<<768, 256, 0, stream>>>(Qh, Kh, Vth, Ob, partA, partB, lpart);
    attn_combine<<<dim3(32, NH), 256, 0, stream>>>(partA, partB, lpart, Ob);
    gemm_out<<<dim3(16, 64), 256, 0, stream>>>(Ob, Wob, bo, out);
}